// Round 15
// baseline (1063.082 us; speedup 1.0000x reference)
//
#include <hip/hip_runtime.h>

#define IN_DIM  512
#define HID_DIM 256
#define OUT_DIM 64
#define KPROP   5
#define ALPHA   0.1f

#define BKT_SHIFT 9            // 512 dst nodes per bucket
#define PART_EPB  8192         // edges per partition block

typedef short short8v __attribute__((ext_vector_type(8)));
typedef float f32x4   __attribute__((ext_vector_type(4)));

__device__ __forceinline__ unsigned short f2bf(float f) {
    unsigned u = __builtin_bit_cast(unsigned, f);
    unsigned r = (u + 0x7FFFu + ((u >> 16) & 1u)) >> 16;
    return (unsigned short)r;
}
__device__ __forceinline__ float bflo(unsigned v) { return __builtin_bit_cast(float, v << 16); }
__device__ __forceinline__ float bfhi(unsigned v) { return __builtin_bit_cast(float, v & 0xffff0000u); }

// ---------------- bucket-level edge count ----------------
__global__ __launch_bounds__(256) void bucket_count_kernel(const int* __restrict__ ei, int E,
                                                           int* __restrict__ bucketCnt) {
    __shared__ int hist[256];
    int t = threadIdx.x;
    hist[t] = 0;
    __syncthreads();
    int e0 = blockIdx.x * PART_EPB;
#pragma unroll 4
    for (int i = 0; i < PART_EPB / 256; ++i) {
        int e = e0 + i * 256 + t;
        if (e < E) atomicAdd(&hist[ei[E + e] >> BKT_SHIFT], 1);
    }
    __syncthreads();
    if (hist[t] > 0) atomicAdd(&bucketCnt[t], hist[t]);
}

// ---------------- bucket scan (1 block) ----------------
__global__ __launch_bounds__(256) void bucket_scan_kernel(const int* __restrict__ bucketCnt,
                                                          int* __restrict__ bucketBase,
                                                          int* __restrict__ bucketFill,
                                                          int* __restrict__ indptr,
                                                          int E, int N) {
    __shared__ int sm[256];
    int t = threadIdx.x;
    int v = bucketCnt[t];
    sm[t] = v;
    __syncthreads();
    for (int off = 1; off < 256; off <<= 1) {
        int add = 0;
        if (t >= off) add = sm[t - off];
        __syncthreads();
        if (t >= off) sm[t] += add;
        __syncthreads();
    }
    int base = sm[t] - v;
    bucketBase[t] = base;
    bucketFill[t] = base;
    if (t == 0) indptr[N] = E;
}

// ---------------- partition; packed = (dst&511)<<17 | src ----------------
__global__ __launch_bounds__(256) void partition_kernel(const int* __restrict__ ei, int E,
                                                        int* __restrict__ bucketFill,
                                                        int* __restrict__ packed) {
    __shared__ int hist[256];
    __shared__ int base[256];
    int t = threadIdx.x;
    int e0 = blockIdx.x * PART_EPB;
    hist[t] = 0;
    __syncthreads();
#pragma unroll 4
    for (int i = 0; i < PART_EPB / 256; ++i) {
        int e = e0 + i * 256 + t;
        if (e < E) atomicAdd(&hist[ei[E + e] >> BKT_SHIFT], 1);
    }
    __syncthreads();
    int cnt = hist[t];
    if (cnt > 0) base[t] = atomicAdd(&bucketFill[t], cnt);
    __syncthreads();
#pragma unroll 4
    for (int i = 0; i < PART_EPB / 256; ++i) {
        int e = e0 + i * 256 + t;
        if (e < E) {
            int dst = ei[E + e];
            int src = ei[e];
            int b = dst >> BKT_SHIFT;
            int pos = atomicAdd(&base[b], 1);
            packed[pos] = ((dst & 511) << 17) | src;
        }
    }
}

// ---------------- fused per-bucket: node hist + indptr + dinv + scatter ----------------
__global__ __launch_bounds__(256) void fine_kernel(const int* __restrict__ packed,
                                                   const int* __restrict__ bucketBase,
                                                   const int* __restrict__ bucketCnt,
                                                   int* __restrict__ csr_row,
                                                   int* __restrict__ indptr,
                                                   float* __restrict__ dinv, int N) {
    __shared__ int cnt[512];
    __shared__ int pre[512];
    __shared__ int fill[512];
    __shared__ int sm[256];
    int b = blockIdx.x;
    int t = threadIdx.x;
    int d0 = b << BKT_SHIFT;
    int nd = N - d0;
    if (nd > 512) nd = 512;
    cnt[t] = 0; cnt[t + 256] = 0;
    fill[t] = 0; fill[t + 256] = 0;
    __syncthreads();
    int beg = bucketBase[b];
    int end = beg + bucketCnt[b];
    for (int e = beg + t; e < end; e += 256)
        atomicAdd(&cnt[((unsigned)packed[e]) >> 17], 1);
    __syncthreads();
    int c0 = cnt[2 * t], c1 = cnt[2 * t + 1];
    int s = c0 + c1;
    sm[t] = s;
    __syncthreads();
    for (int off = 1; off < 256; off <<= 1) {
        int add = 0;
        if (t >= off) add = sm[t - off];
        __syncthreads();
        if (t >= off) sm[t] += add;
        __syncthreads();
    }
    int ex = sm[t] - s;
    pre[2 * t] = ex;
    pre[2 * t + 1] = ex + c0;
    __syncthreads();
    for (int dl = t; dl < nd; dl += 256) {
        indptr[d0 + dl] = beg + pre[dl];
        dinv[d0 + dl] = rsqrtf((float)(cnt[dl] + 1));
    }
    for (int e = beg + t; e < end; e += 256) {
        unsigned p = (unsigned)packed[e];
        int dl = (int)(p >> 17);
        int src = (int)(p & 0x1FFFFu);
        int pos = beg + pre[dl] + atomicAdd(&fill[dl], 1);
        csr_row[pos] = src;
    }
}

// ---------------- weight prep ----------------
__global__ __launch_bounds__(256) void prep_w1_kernel(const float* __restrict__ W1,
                                                      unsigned short* __restrict__ w1p) {
    int idx = blockIdx.x * 256 + threadIdx.x;
    int q = idx >> 14;
    int rem = idx & 16383;
    int c = rem >> 6, j = rem & 63;
    w1p[idx] = f2bf(W1[(size_t)(q * 64 + j) * HID_DIM + c]);
}

__global__ __launch_bounds__(256) void prep_w2_kernel(const float* __restrict__ W2,
                                                      unsigned short* __restrict__ w2p) {
    int idx = blockIdx.x * 256 + threadIdx.x;
    int c = idx >> 8, k = idx & 255;
    w2p[idx] = f2bf(W2[(size_t)k * OUT_DIM + c]);
}

// ---------------- MFMA MLP: exact r10 structure (depth-1 T14, known 120us) ----------------
struct __align__(16) MlpSmem {
    union {
        struct {
            unsigned short xs[64][72];
            unsigned short ws[256][72];
        };
        unsigned short w2s[64][264];
    };
    unsigned short hid[64][264];
};

__device__ __forceinline__ float4 ldx1(const float* __restrict__ x, int row0, int N,
                                       int t, int i, int q) {
    int e = t * 4 + i * 1024;
    int r = e >> 6, j = e & 63;
    if (row0 + r < N) return *(const float4*)&x[(size_t)(row0 + r) * IN_DIM + q * 64 + j];
    return make_float4(0.f, 0.f, 0.f, 0.f);
}

__global__ __launch_bounds__(256, 2) void mlp_mfma_kernel(const float* __restrict__ x,
                                                          const unsigned short* __restrict__ w1p,
                                                          const float* __restrict__ b1,
                                                          const unsigned short* __restrict__ w2p,
                                                          const float* __restrict__ b2,
                                                          float* __restrict__ h0, int N) {
    __shared__ MlpSmem sm;
    int t = threadIdx.x;
    int w = t >> 6, l = t & 63;
    int l15 = l & 15, l4 = l >> 4;
    int wr0 = w * 16;
    int row0 = blockIdx.x * 64;

    f32x4 acc[16];
#pragma unroll
    for (int i = 0; i < 16; ++i) acc[i] = (f32x4){0.f, 0.f, 0.f, 0.f};

    float4 xr0, xr1, xr2, xr3;
    uint4 wv0, wv1, wv2, wv3, wv4, wv5, wv6, wv7;

#define LOADX(q) do { \
        xr0 = ldx1(x, row0, N, t, 0, (q)); \
        xr1 = ldx1(x, row0, N, t, 1, (q)); \
        xr2 = ldx1(x, row0, N, t, 2, (q)); \
        xr3 = ldx1(x, row0, N, t, 3, (q)); \
    } while (0)
#define LOADW(q) do { \
        const unsigned short* _s = w1p + (q) * 16384; \
        wv0 = *(const uint4*)&_s[t * 8 + 0 * 2048]; \
        wv1 = *(const uint4*)&_s[t * 8 + 1 * 2048]; \
        wv2 = *(const uint4*)&_s[t * 8 + 2 * 2048]; \
        wv3 = *(const uint4*)&_s[t * 8 + 3 * 2048]; \
        wv4 = *(const uint4*)&_s[t * 8 + 4 * 2048]; \
        wv5 = *(const uint4*)&_s[t * 8 + 5 * 2048]; \
        wv6 = *(const uint4*)&_s[t * 8 + 6 * 2048]; \
        wv7 = *(const uint4*)&_s[t * 8 + 7 * 2048]; \
    } while (0)
#define STX(i, v) do { \
        int e = t * 4 + (i) * 1024; \
        int r = e >> 6, j = e & 63; \
        unsigned u0 = (unsigned)f2bf((v).x) | ((unsigned)f2bf((v).y) << 16); \
        unsigned u1 = (unsigned)f2bf((v).z) | ((unsigned)f2bf((v).w) << 16); \
        *(uint2*)&sm.xs[r][j] = make_uint2(u0, u1); \
    } while (0)
#define STW(i, v) do { \
        int e = t * 8 + (i) * 2048; \
        int c = e >> 6, j = e & 63; \
        *(uint4*)&sm.ws[c][j] = (v); \
    } while (0)

    LOADX(0);
    LOADW(0);

    for (int q = 0; q < 8; ++q) {
        __syncthreads();
        STX(0, xr0); STX(1, xr1); STX(2, xr2); STX(3, xr3);
        STW(0, wv0); STW(1, wv1); STW(2, wv2); STW(3, wv3);
        STW(4, wv4); STW(5, wv5); STW(6, wv6); STW(7, wv7);
        __syncthreads();
        if (q < 7) {
            LOADX(q + 1);
            LOADW(q + 1);
        }
#pragma unroll
        for (int s = 0; s < 2; ++s) {
            short8v a = *(const short8v*)&sm.xs[wr0 + l15][s * 32 + l4 * 8];
#pragma unroll
            for (int tc = 0; tc < 16; ++tc) {
                short8v b = *(const short8v*)&sm.ws[tc * 16 + l15][s * 32 + l4 * 8];
                acc[tc] = __builtin_amdgcn_mfma_f32_16x16x32_bf16(a, b, acc[tc], 0, 0, 0);
            }
        }
    }
    __syncthreads();

#pragma unroll
    for (int tc = 0; tc < 16; ++tc) {
        float bv = b1[tc * 16 + l15];
#pragma unroll
        for (int i = 0; i < 4; ++i) {
            float v = fmaxf(acc[tc][i] + bv, 0.f);
            sm.hid[wr0 + l4 * 4 + i][tc * 16 + l15] = f2bf(v);
        }
    }
#pragma unroll
    for (int i = 0; i < 8; ++i) {
        int e = t * 8 + i * 2048;
        int c = e >> 8, k = e & 255;
        *(uint4*)&sm.w2s[c][k] = *(const uint4*)&w2p[e];
    }
    __syncthreads();

    f32x4 acc2[4];
#pragma unroll
    for (int i = 0; i < 4; ++i) acc2[i] = (f32x4){0.f, 0.f, 0.f, 0.f};
#pragma unroll
    for (int s = 0; s < 8; ++s) {
        short8v a = *(const short8v*)&sm.hid[wr0 + l15][s * 32 + l4 * 8];
#pragma unroll
        for (int tc = 0; tc < 4; ++tc) {
            short8v b = *(const short8v*)&sm.w2s[tc * 16 + l15][s * 32 + l4 * 8];
            acc2[tc] = __builtin_amdgcn_mfma_f32_16x16x32_bf16(a, b, acc2[tc], 0, 0, 0);
        }
    }
#pragma unroll
    for (int tc = 0; tc < 4; ++tc) {
        float bv = b2[tc * 16 + l15];
#pragma unroll
        for (int i = 0; i < 4; ++i) {
            int row = row0 + wr0 + l4 * 4 + i;
            if (row < N) h0[(size_t)row * OUT_DIM + tc * 16 + l15] = acc2[tc][i] + bv;
        }
    }
#undef LOADX
#undef LOADW
#undef STX
#undef STW
}

// ---------------- hs init -> 4 feature planes: plane[p][node][16] = bf16(dinv*h0) ----------------
__global__ __launch_bounds__(256) void hs_init_kernel(const float* __restrict__ h0,
                                                      const float* __restrict__ dinv,
                                                      unsigned short* __restrict__ hs, int N) {
    int idx = blockIdx.x * 256 + threadIdx.x;  // one per 4 features
    if (idx >= N * 16) return;
    int node = idx >> 4;
    int j = (idx & 15) * 4;                    // feature 0..60
    int p = j >> 4;                            // plane 0..3
    int jf = j & 15;                           // feature within plane
    float d = dinv[node];
    float4 v = *(const float4*)&h0[(size_t)node * 64 + j];
    ushort4 o;
    o.x = f2bf(d * v.x);
    o.y = f2bf(d * v.y);
    o.z = f2bf(d * v.z);
    o.w = f2bf(d * v.w);
    *(ushort4*)&hs[((size_t)p * N + node) * 16 + jf] = o;
}

// ---------------- propagation pass over one 16-feature plane ----------------
// Plane = N x 16 bf16 = 3.2 MB -> fits per-XCD L2 (4 MB): gathers become
// L2-resident (r13 theory: monolithic 128B-row gathers were L3-bound).
// Wave per node: 8 edge-slots x 8 lanes (1 uint = 2 bf16). 2x unrolled.
__global__ __launch_bounds__(256) void prop_plane_kernel(const unsigned short* __restrict__ hsp,
                                                         const float* __restrict__ h0,
                                                         const float* __restrict__ dinv,
                                                         const int* __restrict__ csr_row,
                                                         const int* __restrict__ indptr,
                                                         unsigned short* __restrict__ hsp_out,
                                                         float* __restrict__ hfin,
                                                         int p, int last, int N) {
    int node = blockIdx.x * 4 + (threadIdx.x >> 6);
    if (node >= N) return;
    int l = threadIdx.x & 63;
    int es = l >> 3, fe = l & 7;               // edge slot, feature-pair
    const unsigned* P = (const unsigned*)hsp;  // [N][8] uints
    int beg = indptr[node], end = indptr[node + 1];
    float a0 = 0.f, a1 = 0.f;
    int e = beg;
    for (; e + 16 <= end; e += 16) {           // 16 edges/trip, 2 gathers in flight
        int r0 = csr_row[e + es];
        int r1 = csr_row[e + 8 + es];
        unsigned v0 = P[(size_t)r0 * 8 + fe];
        unsigned v1 = P[(size_t)r1 * 8 + fe];
        a0 += bflo(v0); a1 += bfhi(v0);
        a0 += bflo(v1); a1 += bfhi(v1);
    }
    if (e + 8 <= end) {
        int r = csr_row[e + es];
        unsigned v = P[(size_t)r * 8 + fe];
        a0 += bflo(v); a1 += bfhi(v);
        e += 8;
    }
    if (e + es < end) {                        // masked tail (<8 edges)
        int r = csr_row[e + es];
        unsigned v = P[(size_t)r * 8 + fe];
        a0 += bflo(v); a1 += bfhi(v);
    }
    // reduce across the 8 edge slots (lane bits 3..5)
    a0 += __shfl_xor(a0, 8);  a1 += __shfl_xor(a1, 8);
    a0 += __shfl_xor(a0, 16); a1 += __shfl_xor(a1, 16);
    a0 += __shfl_xor(a0, 32); a1 += __shfl_xor(a1, 32);
    unsigned vs = P[(size_t)node * 8 + fe];    // self loop
    a0 += bflo(vs);
    a1 += bfhi(vs);
    float dcn = dinv[node];
    float2 z = *(const float2*)&h0[(size_t)node * 64 + p * 16 + fe * 2];
    float o0 = (1.0f - ALPHA) * (dcn * a0) + ALPHA * z.x;
    float o1 = (1.0f - ALPHA) * (dcn * a1) + ALPHA * z.y;
    if (es == 0) {
        if (last) {
            *(float2*)&hfin[(size_t)node * 64 + p * 16 + fe * 2] = make_float2(o0, o1);
        } else {
            unsigned pk = (unsigned)f2bf(dcn * o0) | ((unsigned)f2bf(dcn * o1) << 16);
            ((unsigned*)hsp_out)[(size_t)node * 8 + fe] = pk;
        }
    }
}

// ---------------- log_softmax (in-place safe) ----------------
__global__ __launch_bounds__(256) void lsm_kernel(const float* __restrict__ h,
                                                  float* __restrict__ out, int N) {
    int node = blockIdx.x * 4 + (threadIdx.x >> 6);
    if (node >= N) return;
    int lane = threadIdx.x & 63;
    float v = h[(size_t)node * 64 + lane];
    float m = v;
    for (int off = 32; off > 0; off >>= 1) m = fmaxf(m, __shfl_xor(m, off));
    float ex = expf(v - m);
    float s = ex;
    for (int off = 32; off > 0; off >>= 1) s += __shfl_xor(s, off);
    out[(size_t)node * 64 + lane] = (v - m) - logf(s);
}

extern "C" void kernel_launch(void* const* d_in, const int* in_sizes, int n_in,
                              void* d_out, int out_size, void* d_ws, size_t ws_size,
                              hipStream_t stream) {
    const float* x  = (const float*)d_in[0];
    const int*   ei = (const int*)d_in[1];
    const float* W1 = (const float*)d_in[2];
    const float* b1 = (const float*)d_in[3];
    const float* W2 = (const float*)d_in[4];
    const float* b2 = (const float*)d_in[5];
    float* out = (float*)d_out;
    int N = in_sizes[0] / IN_DIM;
    int E = in_sizes[1] / 2;
    int nbkt = (N + 511) >> BKT_SHIFT;

    char* ws = (char*)d_ws;
    size_t off = 0;
    auto alloc = [&](size_t bytes) -> void* {
        void* p = ws + off;
        off += (bytes + 255) & ~(size_t)255;
        return p;
    };
    float* h0     = (float*)alloc((size_t)N * OUT_DIM * 4);
    float* dinv   = (float*)alloc((size_t)N * 4);
    int*   indptr = (int*)alloc((size_t)(N + 1) * 4);
    int*   bcnt   = (int*)alloc(256 * 4);
    int*   bbase  = (int*)alloc(256 * 4);
    int*   bfill  = (int*)alloc(256 * 4);
    int*   packed = (int*)alloc((size_t)E * 4);
    int*   csr_row= (int*)alloc((size_t)E * 4);
    unsigned short* w1p = (unsigned short*)alloc((size_t)IN_DIM * HID_DIM * 2);
    unsigned short* w2p = (unsigned short*)alloc((size_t)HID_DIM * OUT_DIM * 2);
    unsigned short* hsA = (unsigned short*)alloc((size_t)N * OUT_DIM * 2);  // 4 planes
    unsigned short* hsB = (unsigned short*)alloc((size_t)N * OUT_DIM * 2);  // 4 planes
    (void)ws_size; (void)n_in; (void)out_size;

    hipMemsetAsync(bcnt, 0, 256 * 4, stream);

    prep_w1_kernel<<<(IN_DIM * HID_DIM) / 256, 256, 0, stream>>>(W1, w1p);
    prep_w2_kernel<<<(HID_DIM * OUT_DIM) / 256, 256, 0, stream>>>(W2, w2p);

    int pgrid = (E + PART_EPB - 1) / PART_EPB;
    bucket_count_kernel<<<pgrid, 256, 0, stream>>>(ei, E, bcnt);
    bucket_scan_kernel<<<1, 256, 0, stream>>>(bcnt, bbase, bfill, indptr, E, N);
    partition_kernel<<<pgrid, 256, 0, stream>>>(ei, E, bfill, packed);
    fine_kernel<<<nbkt, 256, 0, stream>>>(packed, bbase, bcnt, csr_row, indptr, dinv, N);

    mlp_mfma_kernel<<<(N + 63) / 64, 256, 0, stream>>>(x, w1p, b1, w2p, b2, h0, N);

    hs_init_kernel<<<(N * 16 + 255) / 256, 256, 0, stream>>>(h0, dinv, hsA, N);

    int pb = (N + 3) / 4;
    size_t planeSz = (size_t)N * 16;  // ushorts per plane
    for (int it = 0; it < KPROP; ++it) {
        const unsigned short* hin = (it % 2 == 0) ? hsA : hsB;
        unsigned short* hout = (it % 2 == 0) ? hsB : hsA;
        int last = (it == KPROP - 1) ? 1 : 0;
        for (int p = 0; p < 4; ++p) {
            prop_plane_kernel<<<pb, 256, 0, stream>>>(hin + p * planeSz, h0, dinv,
                                                      csr_row, indptr,
                                                      hout + p * planeSz, out,
                                                      p, last, N);
        }
    }
    lsm_kernel<<<pb, 256, 0, stream>>>(out, out, N);
}

// Round 16
// 568.719 us; speedup vs baseline: 1.8693x; 1.8693x over previous
//
#include <hip/hip_runtime.h>

#define IN_DIM  512
#define HID_DIM 256
#define OUT_DIM 64
#define KPROP   5
#define ALPHA   0.1f

#define BKT_SHIFT 9            // 512 dst nodes per bucket
#define PART_EPB  8192         // edges per partition block

typedef short short8v __attribute__((ext_vector_type(8)));
typedef float f32x4   __attribute__((ext_vector_type(4)));

__device__ __forceinline__ unsigned short f2bf(float f) {
    unsigned u = __builtin_bit_cast(unsigned, f);
    unsigned r = (u + 0x7FFFu + ((u >> 16) & 1u)) >> 16;
    return (unsigned short)r;
}
__device__ __forceinline__ float bflo(unsigned v) { return __builtin_bit_cast(float, v << 16); }
__device__ __forceinline__ float bfhi(unsigned v) { return __builtin_bit_cast(float, v & 0xffff0000u); }

// ---------------- bucket-level edge count ----------------
__global__ __launch_bounds__(256) void bucket_count_kernel(const int* __restrict__ ei, int E,
                                                           int* __restrict__ bucketCnt) {
    __shared__ int hist[256];
    int t = threadIdx.x;
    hist[t] = 0;
    __syncthreads();
    int e0 = blockIdx.x * PART_EPB;
#pragma unroll 4
    for (int i = 0; i < PART_EPB / 256; ++i) {
        int e = e0 + i * 256 + t;
        if (e < E) atomicAdd(&hist[ei[E + e] >> BKT_SHIFT], 1);
    }
    __syncthreads();
    if (hist[t] > 0) atomicAdd(&bucketCnt[t], hist[t]);
}

// ---------------- bucket scan (1 block) ----------------
__global__ __launch_bounds__(256) void bucket_scan_kernel(const int* __restrict__ bucketCnt,
                                                          int* __restrict__ bucketBase,
                                                          int* __restrict__ bucketFill,
                                                          int* __restrict__ indptr,
                                                          int E, int N) {
    __shared__ int sm[256];
    int t = threadIdx.x;
    int v = bucketCnt[t];
    sm[t] = v;
    __syncthreads();
    for (int off = 1; off < 256; off <<= 1) {
        int add = 0;
        if (t >= off) add = sm[t - off];
        __syncthreads();
        if (t >= off) sm[t] += add;
        __syncthreads();
    }
    int base = sm[t] - v;
    bucketBase[t] = base;
    bucketFill[t] = base;
    if (t == 0) indptr[N] = E;
}

// ---------------- partition; packed = (dst&511)<<17 | src ----------------
__global__ __launch_bounds__(256) void partition_kernel(const int* __restrict__ ei, int E,
                                                        int* __restrict__ bucketFill,
                                                        int* __restrict__ packed) {
    __shared__ int hist[256];
    __shared__ int base[256];
    int t = threadIdx.x;
    int e0 = blockIdx.x * PART_EPB;
    hist[t] = 0;
    __syncthreads();
#pragma unroll 4
    for (int i = 0; i < PART_EPB / 256; ++i) {
        int e = e0 + i * 256 + t;
        if (e < E) atomicAdd(&hist[ei[E + e] >> BKT_SHIFT], 1);
    }
    __syncthreads();
    int cnt = hist[t];
    if (cnt > 0) base[t] = atomicAdd(&bucketFill[t], cnt);
    __syncthreads();
#pragma unroll 4
    for (int i = 0; i < PART_EPB / 256; ++i) {
        int e = e0 + i * 256 + t;
        if (e < E) {
            int dst = ei[E + e];
            int src = ei[e];
            int b = dst >> BKT_SHIFT;
            int pos = atomicAdd(&base[b], 1);
            packed[pos] = ((dst & 511) << 17) | src;
        }
    }
}

// ---------------- fused per-bucket: node hist + indptr + dinv + scatter ----------------
__global__ __launch_bounds__(256) void fine_kernel(const int* __restrict__ packed,
                                                   const int* __restrict__ bucketBase,
                                                   const int* __restrict__ bucketCnt,
                                                   int* __restrict__ csr_row,
                                                   int* __restrict__ indptr,
                                                   float* __restrict__ dinv, int N) {
    __shared__ int cnt[512];
    __shared__ int pre[512];
    __shared__ int fill[512];
    __shared__ int sm[256];
    int b = blockIdx.x;
    int t = threadIdx.x;
    int d0 = b << BKT_SHIFT;
    int nd = N - d0;
    if (nd > 512) nd = 512;
    cnt[t] = 0; cnt[t + 256] = 0;
    fill[t] = 0; fill[t + 256] = 0;
    __syncthreads();
    int beg = bucketBase[b];
    int end = beg + bucketCnt[b];
    for (int e = beg + t; e < end; e += 256)
        atomicAdd(&cnt[((unsigned)packed[e]) >> 17], 1);
    __syncthreads();
    int c0 = cnt[2 * t], c1 = cnt[2 * t + 1];
    int s = c0 + c1;
    sm[t] = s;
    __syncthreads();
    for (int off = 1; off < 256; off <<= 1) {
        int add = 0;
        if (t >= off) add = sm[t - off];
        __syncthreads();
        if (t >= off) sm[t] += add;
        __syncthreads();
    }
    int ex = sm[t] - s;
    pre[2 * t] = ex;
    pre[2 * t + 1] = ex + c0;
    __syncthreads();
    for (int dl = t; dl < nd; dl += 256) {
        indptr[d0 + dl] = beg + pre[dl];
        dinv[d0 + dl] = rsqrtf((float)(cnt[dl] + 1));
    }
    for (int e = beg + t; e < end; e += 256) {
        unsigned p = (unsigned)packed[e];
        int dl = (int)(p >> 17);
        int src = (int)(p & 0x1FFFFu);
        int pos = beg + pre[dl] + atomicAdd(&fill[dl], 1);
        csr_row[pos] = src;
    }
}

// ---------------- weight prep ----------------
__global__ __launch_bounds__(256) void prep_w1_kernel(const float* __restrict__ W1,
                                                      unsigned short* __restrict__ w1p) {
    int idx = blockIdx.x * 256 + threadIdx.x;
    int q = idx >> 14;
    int rem = idx & 16383;
    int c = rem >> 6, j = rem & 63;
    w1p[idx] = f2bf(W1[(size_t)(q * 64 + j) * HID_DIM + c]);
}

__global__ __launch_bounds__(256) void prep_w2_kernel(const float* __restrict__ W2,
                                                      unsigned short* __restrict__ w2p) {
    int idx = blockIdx.x * 256 + threadIdx.x;
    int c = idx >> 8, k = idx & 255;
    w2p[idx] = f2bf(W2[(size_t)k * OUT_DIM + c]);
}

// ---------------- MFMA MLP: r10 loop + LDS diet (3 blk/CU) + fused hs epilogue ----------
// Phase-2 (hid + half-of-w2s) overlays the dead xs/ws region: LDS 79.8->50.7KB
// -> 3 blocks/CU (r11 lesson: occupancy is the binding resource). GEMM2 staged
// in two 32-outcol halves. Epilogue also writes hs = bf16(dinv*h0) (kills
// hs_init dispatch + its 38MB re-read).
struct __align__(16) MlpSmem {
    union {
        struct {
            unsigned short xs[64][72];     // 9216 B
            unsigned short ws[256][72];    // 36864 B
        } p1;                              // 46080 B
        struct {
            unsigned short hid[64][264];   // 33792 B
            unsigned short w2s[32][264];   // 16896 B
        } p2;                              // 50688 B  -> LDS total
    };
};

__device__ __forceinline__ float4 ldx1(const float* __restrict__ x, int row0, int N,
                                       int t, int i, int q) {
    int e = t * 4 + i * 1024;
    int r = e >> 6, j = e & 63;
    if (row0 + r < N) return *(const float4*)&x[(size_t)(row0 + r) * IN_DIM + q * 64 + j];
    return make_float4(0.f, 0.f, 0.f, 0.f);
}

__global__ __launch_bounds__(256, 3) void mlp_mfma_kernel(const float* __restrict__ x,
                                                          const unsigned short* __restrict__ w1p,
                                                          const float* __restrict__ b1,
                                                          const unsigned short* __restrict__ w2p,
                                                          const float* __restrict__ b2,
                                                          const float* __restrict__ dinv,
                                                          float* __restrict__ h0,
                                                          unsigned short* __restrict__ hs,
                                                          int N) {
    __shared__ MlpSmem sm;
    int t = threadIdx.x;
    int w = t >> 6, l = t & 63;
    int l15 = l & 15, l4 = l >> 4;
    int wr0 = w * 16;
    int row0 = blockIdx.x * 64;

    f32x4 acc[16];
#pragma unroll
    for (int i = 0; i < 16; ++i) acc[i] = (f32x4){0.f, 0.f, 0.f, 0.f};

    float4 xr0, xr1, xr2, xr3;
    uint4 wv0, wv1, wv2, wv3, wv4, wv5, wv6, wv7;

#define LOADX(q) do { \
        xr0 = ldx1(x, row0, N, t, 0, (q)); \
        xr1 = ldx1(x, row0, N, t, 1, (q)); \
        xr2 = ldx1(x, row0, N, t, 2, (q)); \
        xr3 = ldx1(x, row0, N, t, 3, (q)); \
    } while (0)
#define LOADW(q) do { \
        const unsigned short* _s = w1p + (q) * 16384; \
        wv0 = *(const uint4*)&_s[t * 8 + 0 * 2048]; \
        wv1 = *(const uint4*)&_s[t * 8 + 1 * 2048]; \
        wv2 = *(const uint4*)&_s[t * 8 + 2 * 2048]; \
        wv3 = *(const uint4*)&_s[t * 8 + 3 * 2048]; \
        wv4 = *(const uint4*)&_s[t * 8 + 4 * 2048]; \
        wv5 = *(const uint4*)&_s[t * 8 + 5 * 2048]; \
        wv6 = *(const uint4*)&_s[t * 8 + 6 * 2048]; \
        wv7 = *(const uint4*)&_s[t * 8 + 7 * 2048]; \
    } while (0)
#define STX(i, v) do { \
        int e = t * 4 + (i) * 1024; \
        int r = e >> 6, j = e & 63; \
        unsigned u0 = (unsigned)f2bf((v).x) | ((unsigned)f2bf((v).y) << 16); \
        unsigned u1 = (unsigned)f2bf((v).z) | ((unsigned)f2bf((v).w) << 16); \
        *(uint2*)&sm.p1.xs[r][j] = make_uint2(u0, u1); \
    } while (0)
#define STW(i, v) do { \
        int e = t * 8 + (i) * 2048; \
        int c = e >> 6, j = e & 63; \
        *(uint4*)&sm.p1.ws[c][j] = (v); \
    } while (0)

    LOADX(0);
    LOADW(0);

    for (int q = 0; q < 8; ++q) {
        __syncthreads();
        STX(0, xr0); STX(1, xr1); STX(2, xr2); STX(3, xr3);
        STW(0, wv0); STW(1, wv1); STW(2, wv2); STW(3, wv3);
        STW(4, wv4); STW(5, wv5); STW(6, wv6); STW(7, wv7);
        __syncthreads();
        if (q < 7) {
            LOADX(q + 1);
            LOADW(q + 1);
        }
#pragma unroll
        for (int s = 0; s < 2; ++s) {
            short8v a = *(const short8v*)&sm.p1.xs[wr0 + l15][s * 32 + l4 * 8];
#pragma unroll
            for (int tc = 0; tc < 16; ++tc) {
                short8v b = *(const short8v*)&sm.p1.ws[tc * 16 + l15][s * 32 + l4 * 8];
                acc[tc] = __builtin_amdgcn_mfma_f32_16x16x32_bf16(a, b, acc[tc], 0, 0, 0);
            }
        }
    }
    __syncthreads();  // xs/ws dead; p2 overlay begins

    // epilogue1: bias + relu -> hid (bf16)
#pragma unroll
    for (int tc = 0; tc < 16; ++tc) {
        float bv = b1[tc * 16 + l15];
#pragma unroll
        for (int i = 0; i < 4; ++i) {
            float v = fmaxf(acc[tc][i] + bv, 0.f);
            sm.p2.hid[wr0 + l4 * 4 + i][tc * 16 + l15] = f2bf(v);
        }
    }

    f32x4 acc2[4];
#pragma unroll
    for (int i = 0; i < 4; ++i) acc2[i] = (f32x4){0.f, 0.f, 0.f, 0.f};

    // GEMM2 in two 32-outcol halves (w2s LDS halved for the 3-blk diet)
#pragma unroll
    for (int hf = 0; hf < 2; ++hf) {
        // stage w2p cols [hf*32, hf*32+32): 8192 sh = 4 uint4/thread
#pragma unroll
        for (int i = 0; i < 4; ++i) {
            int e = t * 8 + i * 2048;           // 0..8191 (sh units, local)
            int c = e >> 8, k = e & 255;
            *(uint4*)&sm.p2.w2s[c][k] = *(const uint4*)&w2p[hf * 8192 + e];
        }
        __syncthreads();                        // stage visible (also guards hid on hf=0)
#pragma unroll
        for (int s = 0; s < 8; ++s) {
            short8v a = *(const short8v*)&sm.p2.hid[wr0 + l15][s * 32 + l4 * 8];
#pragma unroll
            for (int tcl = 0; tcl < 2; ++tcl) {
                short8v b = *(const short8v*)&sm.p2.w2s[tcl * 16 + l15][s * 32 + l4 * 8];
                acc2[hf * 2 + tcl] =
                    __builtin_amdgcn_mfma_f32_16x16x32_bf16(a, b, acc2[hf * 2 + tcl], 0, 0, 0);
            }
        }
        __syncthreads();                        // readers done before next restage
    }

    // epilogue2: h0 (fp32) + hs = bf16(dinv * h0)  [fused hs_init]
#pragma unroll
    for (int i = 0; i < 4; ++i) {
        int row = row0 + wr0 + l4 * 4 + i;
        if (row < N) {
            float dv = dinv[row];
#pragma unroll
            for (int tc = 0; tc < 4; ++tc) {
                float v = acc2[tc][i] + b2[tc * 16 + l15];
                h0[(size_t)row * OUT_DIM + tc * 16 + l15] = v;
                hs[(size_t)row * OUT_DIM + tc * 16 + l15] = f2bf(dv * v);
            }
        }
    }
#undef LOADX
#undef LOADW
#undef STX
#undef STW
}

// ---------------- propagation, bf16 prescaled + idx pipeline + fused lsm on last ----
__global__ __launch_bounds__(256) void prop_bf16_kernel(const unsigned short* __restrict__ hs,
                                                        const float* __restrict__ h0,
                                                        const float* __restrict__ dinv,
                                                        const int* __restrict__ csr_row,
                                                        const int* __restrict__ indptr,
                                                        unsigned short* __restrict__ hs_out,
                                                        float* __restrict__ hfin,
                                                        int last, int N) {
    int node = blockIdx.x * 4 + (threadIdx.x >> 6);
    if (node >= N) return;
    int l = threadIdx.x & 63;
    int half = l >> 5, li = l & 31;
    const unsigned* hs32 = (const unsigned*)hs;
    int beg = indptr[node], end = indptr[node + 1];
    float a0 = 0.f, a1 = 0.f;
    int e = beg;
    if (e + 8 <= end) {
        int r0 = csr_row[e + 0 + half];
        int r1 = csr_row[e + 2 + half];
        int r2 = csr_row[e + 4 + half];
        int r3 = csr_row[e + 6 + half];
        while (true) {
            int eb = (e + 16 <= end) ? (e + 8) : beg;
            int n0 = csr_row[eb + 0 + half];
            int n1 = csr_row[eb + 2 + half];
            int n2 = csr_row[eb + 4 + half];
            int n3 = csr_row[eb + 6 + half];
            unsigned v0 = hs32[(size_t)r0 * 32 + li];
            unsigned v1 = hs32[(size_t)r1 * 32 + li];
            unsigned v2 = hs32[(size_t)r2 * 32 + li];
            unsigned v3 = hs32[(size_t)r3 * 32 + li];
            a0 += bflo(v0); a1 += bfhi(v0);
            a0 += bflo(v1); a1 += bfhi(v1);
            a0 += bflo(v2); a1 += bfhi(v2);
            a0 += bflo(v3); a1 += bfhi(v3);
            e += 8;
            if (e + 8 > end) break;
            r0 = n0; r1 = n1; r2 = n2; r3 = n3;
        }
    }
    for (; e + 2 <= end; e += 2) {
        int r = csr_row[e + half];
        unsigned v = hs32[(size_t)r * 32 + li];
        a0 += bflo(v); a1 += bfhi(v);
    }
    if (e < end && half == 0) {
        int r = csr_row[e];
        unsigned v = hs32[(size_t)r * 32 + li];
        a0 += bflo(v); a1 += bfhi(v);
    }
    a0 += __shfl_xor(a0, 32);
    a1 += __shfl_xor(a1, 32);
    unsigned vs = hs32[(size_t)node * 32 + li];  // self loop
    a0 += bflo(vs);
    a1 += bfhi(vs);
    float dcn = dinv[node];
    float2 z = *(const float2*)&h0[(size_t)node * 64 + li * 2];
    float o0 = (1.0f - ALPHA) * (dcn * a0) + ALPHA * z.x;
    float o1 = (1.0f - ALPHA) * (dcn * a1) + ALPHA * z.y;
    if (last) {
        // fused log_softmax: halves hold duplicated li-values; widths 1..16 stay in-half
        float m = fmaxf(o0, o1);
        m = fmaxf(m, __shfl_xor(m, 1));
        m = fmaxf(m, __shfl_xor(m, 2));
        m = fmaxf(m, __shfl_xor(m, 4));
        m = fmaxf(m, __shfl_xor(m, 8));
        m = fmaxf(m, __shfl_xor(m, 16));
        float s = expf(o0 - m) + expf(o1 - m);
        s += __shfl_xor(s, 1);
        s += __shfl_xor(s, 2);
        s += __shfl_xor(s, 4);
        s += __shfl_xor(s, 8);
        s += __shfl_xor(s, 16);
        float lg = logf(s);
        if (half == 0)
            *(float2*)&hfin[(size_t)node * 64 + li * 2] =
                make_float2(o0 - m - lg, o1 - m - lg);
    } else if (half == 0) {
        unsigned p = (unsigned)f2bf(dcn * o0) | ((unsigned)f2bf(dcn * o1) << 16);
        ((unsigned*)hs_out)[(size_t)node * 32 + li] = p;
    }
}

extern "C" void kernel_launch(void* const* d_in, const int* in_sizes, int n_in,
                              void* d_out, int out_size, void* d_ws, size_t ws_size,
                              hipStream_t stream) {
    const float* x  = (const float*)d_in[0];
    const int*   ei = (const int*)d_in[1];
    const float* W1 = (const float*)d_in[2];
    const float* b1 = (const float*)d_in[3];
    const float* W2 = (const float*)d_in[4];
    const float* b2 = (const float*)d_in[5];
    float* out = (float*)d_out;
    int N = in_sizes[0] / IN_DIM;
    int E = in_sizes[1] / 2;
    int nbkt = (N + 511) >> BKT_SHIFT;

    char* ws = (char*)d_ws;
    size_t off = 0;
    auto alloc = [&](size_t bytes) -> void* {
        void* p = ws + off;
        off += (bytes + 255) & ~(size_t)255;
        return p;
    };
    float* h0     = (float*)alloc((size_t)N * OUT_DIM * 4);
    float* dinv   = (float*)alloc((size_t)N * 4);
    int*   indptr = (int*)alloc((size_t)(N + 1) * 4);
    int*   bcnt   = (int*)alloc(256 * 4);
    int*   bbase  = (int*)alloc(256 * 4);
    int*   bfill  = (int*)alloc(256 * 4);
    int*   packed = (int*)alloc((size_t)E * 4);
    int*   csr_row= (int*)alloc((size_t)E * 4);
    unsigned short* w1p = (unsigned short*)alloc((size_t)IN_DIM * HID_DIM * 2);
    unsigned short* w2p = (unsigned short*)alloc((size_t)HID_DIM * OUT_DIM * 2);
    unsigned short* hsA = (unsigned short*)alloc((size_t)N * OUT_DIM * 2);
    unsigned short* hsB = (unsigned short*)alloc((size_t)N * OUT_DIM * 2);
    (void)ws_size; (void)n_in; (void)out_size;

    hipMemsetAsync(bcnt, 0, 256 * 4, stream);

    prep_w1_kernel<<<(IN_DIM * HID_DIM) / 256, 256, 0, stream>>>(W1, w1p);
    prep_w2_kernel<<<(HID_DIM * OUT_DIM) / 256, 256, 0, stream>>>(W2, w2p);

    int pgrid = (E + PART_EPB - 1) / PART_EPB;
    bucket_count_kernel<<<pgrid, 256, 0, stream>>>(ei, E, bcnt);
    bucket_scan_kernel<<<1, 256, 0, stream>>>(bcnt, bbase, bfill, indptr, E, N);
    partition_kernel<<<pgrid, 256, 0, stream>>>(ei, E, bfill, packed);
    fine_kernel<<<nbkt, 256, 0, stream>>>(packed, bbase, bcnt, csr_row, indptr, dinv, N);

    mlp_mfma_kernel<<<(N + 63) / 64, 256, 0, stream>>>(x, w1p, b1, w2p, b2, dinv,
                                                       h0, hsA, N);

    int pb = (N + 3) / 4;
    for (int it = 0; it < KPROP; ++it) {
        const unsigned short* hin = (it % 2 == 0) ? hsA : hsB;
        unsigned short* hout = (it % 2 == 0) ? hsB : hsA;
        int last = (it == KPROP - 1) ? 1 : 0;
        prop_bf16_kernel<<<pb, 256, 0, stream>>>(hin, h0, dinv, csr_row, indptr,
                                                 hout, out, last, N);
    }
}

// Round 17
// 529.899 us; speedup vs baseline: 2.0062x; 1.0733x over previous
//
#include <hip/hip_runtime.h>

#define IN_DIM  512
#define HID_DIM 256
#define OUT_DIM 64
#define KPROP   5
#define ALPHA   0.1f

#define BKT_SHIFT 9            // 512 dst nodes per bucket
#define PART_EPB  8192         // edges per partition block

typedef short short8v __attribute__((ext_vector_type(8)));
typedef float f32x4   __attribute__((ext_vector_type(4)));
typedef float f32x2   __attribute__((ext_vector_type(2)));

__device__ __forceinline__ unsigned short f2bf(float f) {
    unsigned u = __builtin_bit_cast(unsigned, f);
    unsigned r = (u + 0x7FFFu + ((u >> 16) & 1u)) >> 16;
    return (unsigned short)r;
}

// ---------------- bucket-level edge count ----------------
__global__ __launch_bounds__(256) void bucket_count_kernel(const int* __restrict__ ei, int E,
                                                           int* __restrict__ bucketCnt) {
    __shared__ int hist[256];
    int t = threadIdx.x;
    hist[t] = 0;
    __syncthreads();
    int e0 = blockIdx.x * PART_EPB;
#pragma unroll 4
    for (int i = 0; i < PART_EPB / 256; ++i) {
        int e = e0 + i * 256 + t;
        if (e < E) atomicAdd(&hist[ei[E + e] >> BKT_SHIFT], 1);
    }
    __syncthreads();
    if (hist[t] > 0) atomicAdd(&bucketCnt[t], hist[t]);
}

// ---------------- bucket scan (1 block) ----------------
__global__ __launch_bounds__(256) void bucket_scan_kernel(const int* __restrict__ bucketCnt,
                                                          int* __restrict__ bucketBase,
                                                          int* __restrict__ bucketFill,
                                                          int* __restrict__ indptr,
                                                          int E, int N) {
    __shared__ int sm[256];
    int t = threadIdx.x;
    int v = bucketCnt[t];
    sm[t] = v;
    __syncthreads();
    for (int off = 1; off < 256; off <<= 1) {
        int add = 0;
        if (t >= off) add = sm[t - off];
        __syncthreads();
        if (t >= off) sm[t] += add;
        __syncthreads();
    }
    int base = sm[t] - v;
    bucketBase[t] = base;
    bucketFill[t] = base;
    if (t == 0) indptr[N] = E;
}

// ---------------- partition; packed = (dst&511)<<17 | src ----------------
__global__ __launch_bounds__(256) void partition_kernel(const int* __restrict__ ei, int E,
                                                        int* __restrict__ bucketFill,
                                                        int* __restrict__ packed) {
    __shared__ int hist[256];
    __shared__ int base[256];
    int t = threadIdx.x;
    int e0 = blockIdx.x * PART_EPB;
    hist[t] = 0;
    __syncthreads();
#pragma unroll 4
    for (int i = 0; i < PART_EPB / 256; ++i) {
        int e = e0 + i * 256 + t;
        if (e < E) atomicAdd(&hist[ei[E + e] >> BKT_SHIFT], 1);
    }
    __syncthreads();
    int cnt = hist[t];
    if (cnt > 0) base[t] = atomicAdd(&bucketFill[t], cnt);
    __syncthreads();
#pragma unroll 4
    for (int i = 0; i < PART_EPB / 256; ++i) {
        int e = e0 + i * 256 + t;
        if (e < E) {
            int dst = ei[E + e];
            int src = ei[e];
            int b = dst >> BKT_SHIFT;
            int pos = atomicAdd(&base[b], 1);
            packed[pos] = ((dst & 511) << 17) | src;
        }
    }
}

// ---------------- fused per-bucket: node hist + indptr + dinv + scatter ----------------
__global__ __launch_bounds__(256) void fine_kernel(const int* __restrict__ packed,
                                                   const int* __restrict__ bucketBase,
                                                   const int* __restrict__ bucketCnt,
                                                   int* __restrict__ csr_row,
                                                   int* __restrict__ indptr,
                                                   float* __restrict__ dinv, int N) {
    __shared__ int cnt[512];
    __shared__ int pre[512];
    __shared__ int fill[512];
    __shared__ int sm[256];
    int b = blockIdx.x;
    int t = threadIdx.x;
    int d0 = b << BKT_SHIFT;
    int nd = N - d0;
    if (nd > 512) nd = 512;
    cnt[t] = 0; cnt[t + 256] = 0;
    fill[t] = 0; fill[t + 256] = 0;
    __syncthreads();
    int beg = bucketBase[b];
    int end = beg + bucketCnt[b];
    for (int e = beg + t; e < end; e += 256)
        atomicAdd(&cnt[((unsigned)packed[e]) >> 17], 1);
    __syncthreads();
    int c0 = cnt[2 * t], c1 = cnt[2 * t + 1];
    int s = c0 + c1;
    sm[t] = s;
    __syncthreads();
    for (int off = 1; off < 256; off <<= 1) {
        int add = 0;
        if (t >= off) add = sm[t - off];
        __syncthreads();
        if (t >= off) sm[t] += add;
        __syncthreads();
    }
    int ex = sm[t] - s;
    pre[2 * t] = ex;
    pre[2 * t + 1] = ex + c0;
    __syncthreads();
    for (int dl = t; dl < nd; dl += 256) {
        indptr[d0 + dl] = beg + pre[dl];
        dinv[d0 + dl] = rsqrtf((float)(cnt[dl] + 1));
    }
    for (int e = beg + t; e < end; e += 256) {
        unsigned p = (unsigned)packed[e];
        int dl = (int)(p >> 17);
        int src = (int)(p & 0x1FFFFu);
        int pos = beg + pre[dl] + atomicAdd(&fill[dl], 1);
        csr_row[pos] = src;
    }
}

// ---------------- weight prep ----------------
__global__ __launch_bounds__(256) void prep_w1_kernel(const float* __restrict__ W1,
                                                      unsigned short* __restrict__ w1p) {
    int idx = blockIdx.x * 256 + threadIdx.x;
    int q = idx >> 14;
    int rem = idx & 16383;
    int c = rem >> 6, j = rem & 63;
    w1p[idx] = f2bf(W1[(size_t)(q * 64 + j) * HID_DIM + c]);
}

__global__ __launch_bounds__(256) void prep_w2_kernel(const float* __restrict__ W2,
                                                      unsigned short* __restrict__ w2p) {
    int idx = blockIdx.x * 256 + threadIdx.x;
    int c = idx >> 8, k = idx & 255;
    w2p[idx] = f2bf(W2[(size_t)k * OUT_DIM + c]);
}

// ---------------- MFMA MLP: r16 structure; epilogue writes fp8 hs ----------------
struct __align__(16) MlpSmem {
    union {
        struct {
            unsigned short xs[64][72];     // 9216 B
            unsigned short ws[256][72];    // 36864 B
        } p1;
        struct {
            unsigned short hid[64][264];   // 33792 B
            unsigned short w2s[32][264];   // 16896 B
        } p2;                              // 50688 B LDS -> 3 blocks/CU
    };
};

__device__ __forceinline__ float4 ldx1(const float* __restrict__ x, int row0, int N,
                                       int t, int i, int q) {
    int e = t * 4 + i * 1024;
    int r = e >> 6, j = e & 63;
    if (row0 + r < N) return *(const float4*)&x[(size_t)(row0 + r) * IN_DIM + q * 64 + j];
    return make_float4(0.f, 0.f, 0.f, 0.f);
}

__global__ __launch_bounds__(256, 3) void mlp_mfma_kernel(const float* __restrict__ x,
                                                          const unsigned short* __restrict__ w1p,
                                                          const float* __restrict__ b1,
                                                          const unsigned short* __restrict__ w2p,
                                                          const float* __restrict__ b2,
                                                          const float* __restrict__ dinv,
                                                          float* __restrict__ h0,
                                                          unsigned char* __restrict__ hs,
                                                          int N) {
    __shared__ MlpSmem sm;
    int t = threadIdx.x;
    int w = t >> 6, l = t & 63;
    int l15 = l & 15, l4 = l >> 4;
    int wr0 = w * 16;
    int row0 = blockIdx.x * 64;

    f32x4 acc[16];
#pragma unroll
    for (int i = 0; i < 16; ++i) acc[i] = (f32x4){0.f, 0.f, 0.f, 0.f};

    float4 xr0, xr1, xr2, xr3;
    uint4 wv0, wv1, wv2, wv3, wv4, wv5, wv6, wv7;

#define LOADX(q) do { \
        xr0 = ldx1(x, row0, N, t, 0, (q)); \
        xr1 = ldx1(x, row0, N, t, 1, (q)); \
        xr2 = ldx1(x, row0, N, t, 2, (q)); \
        xr3 = ldx1(x, row0, N, t, 3, (q)); \
    } while (0)
#define LOADW(q) do { \
        const unsigned short* _s = w1p + (q) * 16384; \
        wv0 = *(const uint4*)&_s[t * 8 + 0 * 2048]; \
        wv1 = *(const uint4*)&_s[t * 8 + 1 * 2048]; \
        wv2 = *(const uint4*)&_s[t * 8 + 2 * 2048]; \
        wv3 = *(const uint4*)&_s[t * 8 + 3 * 2048]; \
        wv4 = *(const uint4*)&_s[t * 8 + 4 * 2048]; \
        wv5 = *(const uint4*)&_s[t * 8 + 5 * 2048]; \
        wv6 = *(const uint4*)&_s[t * 8 + 6 * 2048]; \
        wv7 = *(const uint4*)&_s[t * 8 + 7 * 2048]; \
    } while (0)
#define STX(i, v) do { \
        int e = t * 4 + (i) * 1024; \
        int r = e >> 6, j = e & 63; \
        unsigned u0 = (unsigned)f2bf((v).x) | ((unsigned)f2bf((v).y) << 16); \
        unsigned u1 = (unsigned)f2bf((v).z) | ((unsigned)f2bf((v).w) << 16); \
        *(uint2*)&sm.p1.xs[r][j] = make_uint2(u0, u1); \
    } while (0)
#define STW(i, v) do { \
        int e = t * 8 + (i) * 2048; \
        int c = e >> 6, j = e & 63; \
        *(uint4*)&sm.p1.ws[c][j] = (v); \
    } while (0)

    LOADX(0);
    LOADW(0);

    for (int q = 0; q < 8; ++q) {
        __syncthreads();
        STX(0, xr0); STX(1, xr1); STX(2, xr2); STX(3, xr3);
        STW(0, wv0); STW(1, wv1); STW(2, wv2); STW(3, wv3);
        STW(4, wv4); STW(5, wv5); STW(6, wv6); STW(7, wv7);
        __syncthreads();
        if (q < 7) {
            LOADX(q + 1);
            LOADW(q + 1);
        }
#pragma unroll
        for (int s = 0; s < 2; ++s) {
            short8v a = *(const short8v*)&sm.p1.xs[wr0 + l15][s * 32 + l4 * 8];
#pragma unroll
            for (int tc = 0; tc < 16; ++tc) {
                short8v b = *(const short8v*)&sm.p1.ws[tc * 16 + l15][s * 32 + l4 * 8];
                acc[tc] = __builtin_amdgcn_mfma_f32_16x16x32_bf16(a, b, acc[tc], 0, 0, 0);
            }
        }
    }
    __syncthreads();  // xs/ws dead; p2 overlay begins

#pragma unroll
    for (int tc = 0; tc < 16; ++tc) {
        float bv = b1[tc * 16 + l15];
#pragma unroll
        for (int i = 0; i < 4; ++i) {
            float v = fmaxf(acc[tc][i] + bv, 0.f);
            sm.p2.hid[wr0 + l4 * 4 + i][tc * 16 + l15] = f2bf(v);
        }
    }

    f32x4 acc2[4];
#pragma unroll
    for (int i = 0; i < 4; ++i) acc2[i] = (f32x4){0.f, 0.f, 0.f, 0.f};

#pragma unroll
    for (int hf = 0; hf < 2; ++hf) {
#pragma unroll
        for (int i = 0; i < 4; ++i) {
            int e = t * 8 + i * 2048;
            int c = e >> 8, k = e & 255;
            *(uint4*)&sm.p2.w2s[c][k] = *(const uint4*)&w2p[hf * 8192 + e];
        }
        __syncthreads();
#pragma unroll
        for (int s = 0; s < 8; ++s) {
            short8v a = *(const short8v*)&sm.p2.hid[wr0 + l15][s * 32 + l4 * 8];
#pragma unroll
            for (int tcl = 0; tcl < 2; ++tcl) {
                short8v b = *(const short8v*)&sm.p2.w2s[tcl * 16 + l15][s * 32 + l4 * 8];
                acc2[hf * 2 + tcl] =
                    __builtin_amdgcn_mfma_f32_16x16x32_bf16(a, b, acc2[hf * 2 + tcl], 0, 0, 0);
            }
        }
        __syncthreads();
    }

    // epilogue2: h0 (fp32) + hs = fp8_e4m3(dinv * h0)
#pragma unroll
    for (int i = 0; i < 4; ++i) {
        int row = row0 + wr0 + l4 * 4 + i;
        if (row < N) {
            float dv = dinv[row];
#pragma unroll
            for (int tc = 0; tc < 4; ++tc) {
                float v = acc2[tc][i] + b2[tc * 16 + l15];
                h0[(size_t)row * OUT_DIM + tc * 16 + l15] = v;
                float sv = dv * v;
                int pk = __builtin_amdgcn_cvt_pk_fp8_f32(sv, sv, 0, false);
                hs[(size_t)row * OUT_DIM + tc * 16 + l15] = (unsigned char)(pk & 0xFF);
            }
        }
    }
#undef LOADX
#undef LOADW
#undef STX
#undef STW
}

// ---------------- propagation, fp8 prescaled rows (64B = 1 line per edge) ----------
// wave per node; lane = (q = l>>4 edge-slot, lf = l&15 feature-quad).
// Gather H[r*16+lf] (uint = 4 fp8), HW-decode, accumulate 4 f32/lane.
// Reduce across quarters (xor 16,32); self loop after reduce; fused lsm on last.
__global__ __launch_bounds__(256) void prop_fp8_kernel(const unsigned char* __restrict__ hs,
                                                       const float* __restrict__ h0,
                                                       const float* __restrict__ dinv,
                                                       const int* __restrict__ csr_row,
                                                       const int* __restrict__ indptr,
                                                       unsigned char* __restrict__ hs_out,
                                                       float* __restrict__ hfin,
                                                       int last, int N) {
    int node = blockIdx.x * 4 + (threadIdx.x >> 6);
    if (node >= N) return;
    int l = threadIdx.x & 63;
    int q = l >> 4, lf = l & 15;
    const unsigned* H = (const unsigned*)hs;   // [N][16] uints
    int beg = indptr[node], end = indptr[node + 1];
    float a0 = 0.f, a1 = 0.f, a2 = 0.f, a3 = 0.f;
#define ACCU(u) do { \
        f32x2 _f01 = __builtin_amdgcn_cvt_pk_f32_fp8((int)(u), false); \
        f32x2 _f23 = __builtin_amdgcn_cvt_pk_f32_fp8((int)(u), true);  \
        a0 += _f01[0]; a1 += _f01[1]; a2 += _f23[0]; a3 += _f23[1];    \
    } while (0)
    int e = beg;
    if (e + 8 <= end) {
        int r0 = csr_row[e + q];
        int r1 = csr_row[e + 4 + q];
        while (true) {
            int eb = (e + 16 <= end) ? (e + 8) : beg;  // clamped prefetch
            int n0 = csr_row[eb + q];
            int n1 = csr_row[eb + 4 + q];
            unsigned u0 = H[(size_t)r0 * 16 + lf];
            unsigned u1 = H[(size_t)r1 * 16 + lf];
            ACCU(u0);
            ACCU(u1);
            e += 8;
            if (e + 8 > end) break;
            r0 = n0; r1 = n1;
        }
    }
    if (e + 4 <= end) {
        int r = csr_row[e + q];
        ACCU(H[(size_t)r * 16 + lf]);
        e += 4;
    }
    if (e + q < end) {  // masked tail (<4 edges)
        int r = csr_row[e + q];
        ACCU(H[(size_t)r * 16 + lf]);
    }
    // reduce across the 4 edge-slots (lane bits 4,5)
    a0 += __shfl_xor(a0, 16); a1 += __shfl_xor(a1, 16);
    a2 += __shfl_xor(a2, 16); a3 += __shfl_xor(a3, 16);
    a0 += __shfl_xor(a0, 32); a1 += __shfl_xor(a1, 32);
    a2 += __shfl_xor(a2, 32); a3 += __shfl_xor(a3, 32);
    ACCU(H[(size_t)node * 16 + lf]);  // self loop (once, post-reduce; uniform across quarters)
#undef ACCU
    float dcn = dinv[node];
    if (last) {
        float4 z = *(const float4*)&h0[(size_t)node * 64 + lf * 4];
        float o0 = (1.0f - ALPHA) * (dcn * a0) + ALPHA * z.x;
        float o1 = (1.0f - ALPHA) * (dcn * a1) + ALPHA * z.y;
        float o2 = (1.0f - ALPHA) * (dcn * a2) + ALPHA * z.z;
        float o3 = (1.0f - ALPHA) * (dcn * a3) + ALPHA * z.w;
        // fused log_softmax: all lanes hold full sums; row spans the 16 lf lanes
        float m = fmaxf(fmaxf(o0, o1), fmaxf(o2, o3));
        m = fmaxf(m, __shfl_xor(m, 1));
        m = fmaxf(m, __shfl_xor(m, 2));
        m = fmaxf(m, __shfl_xor(m, 4));
        m = fmaxf(m, __shfl_xor(m, 8));
        float s = expf(o0 - m) + expf(o1 - m) + expf(o2 - m) + expf(o3 - m);
        s += __shfl_xor(s, 1);
        s += __shfl_xor(s, 2);
        s += __shfl_xor(s, 4);
        s += __shfl_xor(s, 8);
        float lg = logf(s);
        if (q == 0) {
            float4 o;
            o.x = o0 - m - lg; o.y = o1 - m - lg; o.z = o2 - m - lg; o.w = o3 - m - lg;
            *(float4*)&hfin[(size_t)node * 64 + lf * 4] = o;
        }
    } else if (q == 0) {
        float4 z = *(const float4*)&h0[(size_t)node * 64 + lf * 4];
        float o0 = (1.0f - ALPHA) * (dcn * a0) + ALPHA * z.x;
        float o1 = (1.0f - ALPHA) * (dcn * a1) + ALPHA * z.y;
        float o2 = (1.0f - ALPHA) * (dcn * a2) + ALPHA * z.z;
        float o3 = (1.0f - ALPHA) * (dcn * a3) + ALPHA * z.w;
        int wpk = __builtin_amdgcn_cvt_pk_fp8_f32(dcn * o0, dcn * o1, 0, false);
        wpk = __builtin_amdgcn_cvt_pk_fp8_f32(dcn * o2, dcn * o3, wpk, true);
        ((unsigned*)hs_out)[(size_t)node * 16 + lf] = (unsigned)wpk;
    }
}

extern "C" void kernel_launch(void* const* d_in, const int* in_sizes, int n_in,
                              void* d_out, int out_size, void* d_ws, size_t ws_size,
                              hipStream_t stream) {
    const float* x  = (const float*)d_in[0];
    const int*   ei = (const int*)d_in[1];
    const float* W1 = (const float*)d_in[2];
    const float* b1 = (const float*)d_in[3];
    const float* W2 = (const float*)d_in[4];
    const float* b2 = (const float*)d_in[5];
    float* out = (float*)d_out;
    int N = in_sizes[0] / IN_DIM;
    int E = in_sizes[1] / 2;
    int nbkt = (N + 511) >> BKT_SHIFT;

    char* ws = (char*)d_ws;
    size_t off = 0;
    auto alloc = [&](size_t bytes) -> void* {
        void* p = ws + off;
        off += (bytes + 255) & ~(size_t)255;
        return p;
    };
    float* h0     = (float*)alloc((size_t)N * OUT_DIM * 4);
    float* dinv   = (float*)alloc((size_t)N * 4);
    int*   indptr = (int*)alloc((size_t)(N + 1) * 4);
    int*   bcnt   = (int*)alloc(256 * 4);
    int*   bbase  = (int*)alloc(256 * 4);
    int*   bfill  = (int*)alloc(256 * 4);
    int*   packed = (int*)alloc((size_t)E * 4);
    int*   csr_row= (int*)alloc((size_t)E * 4);
    unsigned short* w1p = (unsigned short*)alloc((size_t)IN_DIM * HID_DIM * 2);
    unsigned short* w2p = (unsigned short*)alloc((size_t)HID_DIM * OUT_DIM * 2);
    unsigned char* hsA = (unsigned char*)alloc((size_t)N * OUT_DIM);  // fp8
    unsigned char* hsB = (unsigned char*)alloc((size_t)N * OUT_DIM);  // fp8
    (void)ws_size; (void)n_in; (void)out_size;

    hipMemsetAsync(bcnt, 0, 256 * 4, stream);

    prep_w1_kernel<<<(IN_DIM * HID_DIM) / 256, 256, 0, stream>>>(W1, w1p);
    prep_w2_kernel<<<(HID_DIM * OUT_DIM) / 256, 256, 0, stream>>>(W2, w2p);

    int pgrid = (E + PART_EPB - 1) / PART_EPB;
    bucket_count_kernel<<<pgrid, 256, 0, stream>>>(ei, E, bcnt);
    bucket_scan_kernel<<<1, 256, 0, stream>>>(bcnt, bbase, bfill, indptr, E, N);
    partition_kernel<<<pgrid, 256, 0, stream>>>(ei, E, bfill, packed);
    fine_kernel<<<nbkt, 256, 0, stream>>>(packed, bbase, bcnt, csr_row, indptr, dinv, N);

    mlp_mfma_kernel<<<(N + 63) / 64, 256, 0, stream>>>(x, w1p, b1, w2p, b2, dinv,
                                                       h0, hsA, N);

    int pb = (N + 3) / 4;
    for (int it = 0; it < KPROP; ++it) {
        const unsigned char* hin = (it % 2 == 0) ? hsA : hsB;
        unsigned char* hout = (it % 2 == 0) ? hsB : hsA;
        int last = (it == KPROP - 1) ? 1 : 0;
        prop_fp8_kernel<<<pb, 256, 0, stream>>>(hin, h0, dinv, csr_row, indptr,
                                                hout, out, last, N);
    }
}

// Round 18
// 480.896 us; speedup vs baseline: 2.2106x; 1.1019x over previous
//
#include <hip/hip_runtime.h>

#define IN_DIM  512
#define HID_DIM 256
#define OUT_DIM 64
#define KPROP   5
#define ALPHA   0.1f

#define BKT_SHIFT 9            // 512 dst nodes per bucket
#define PART_EPB  8192         // edges per partition block

typedef short short8v __attribute__((ext_vector_type(8)));
typedef float f32x4   __attribute__((ext_vector_type(4)));
typedef float f32x2   __attribute__((ext_vector_type(2)));

__device__ __forceinline__ unsigned short f2bf(float f) {
    unsigned u = __builtin_bit_cast(unsigned, f);
    unsigned r = (u + 0x7FFFu + ((u >> 16) & 1u)) >> 16;
    return (unsigned short)r;
}

// ---------------- bucket-level edge count ----------------
__global__ __launch_bounds__(256) void bucket_count_kernel(const int* __restrict__ ei, int E,
                                                           int* __restrict__ bucketCnt) {
    __shared__ int hist[256];
    int t = threadIdx.x;
    hist[t] = 0;
    __syncthreads();
    int e0 = blockIdx.x * PART_EPB;
#pragma unroll 4
    for (int i = 0; i < PART_EPB / 256; ++i) {
        int e = e0 + i * 256 + t;
        if (e < E) atomicAdd(&hist[ei[E + e] >> BKT_SHIFT], 1);
    }
    __syncthreads();
    if (hist[t] > 0) atomicAdd(&bucketCnt[t], hist[t]);
}

// ---------------- bucket scan (1 block) ----------------
__global__ __launch_bounds__(256) void bucket_scan_kernel(const int* __restrict__ bucketCnt,
                                                          int* __restrict__ bucketBase,
                                                          int* __restrict__ bucketFill,
                                                          int* __restrict__ indptr,
                                                          int E, int N) {
    __shared__ int sm[256];
    int t = threadIdx.x;
    int v = bucketCnt[t];
    sm[t] = v;
    __syncthreads();
    for (int off = 1; off < 256; off <<= 1) {
        int add = 0;
        if (t >= off) add = sm[t - off];
        __syncthreads();
        if (t >= off) sm[t] += add;
        __syncthreads();
    }
    int base = sm[t] - v;
    bucketBase[t] = base;
    bucketFill[t] = base;
    if (t == 0) indptr[N] = E;
}

// ---------------- partition; packed = (dst&511)<<17 | src ----------------
__global__ __launch_bounds__(256) void partition_kernel(const int* __restrict__ ei, int E,
                                                        int* __restrict__ bucketFill,
                                                        int* __restrict__ packed) {
    __shared__ int hist[256];
    __shared__ int base[256];
    int t = threadIdx.x;
    int e0 = blockIdx.x * PART_EPB;
    hist[t] = 0;
    __syncthreads();
#pragma unroll 4
    for (int i = 0; i < PART_EPB / 256; ++i) {
        int e = e0 + i * 256 + t;
        if (e < E) atomicAdd(&hist[ei[E + e] >> BKT_SHIFT], 1);
    }
    __syncthreads();
    int cnt = hist[t];
    if (cnt > 0) base[t] = atomicAdd(&bucketFill[t], cnt);
    __syncthreads();
#pragma unroll 4
    for (int i = 0; i < PART_EPB / 256; ++i) {
        int e = e0 + i * 256 + t;
        if (e < E) {
            int dst = ei[E + e];
            int src = ei[e];
            int b = dst >> BKT_SHIFT;
            int pos = atomicAdd(&base[b], 1);
            packed[pos] = ((dst & 511) << 17) | src;
        }
    }
}

// ---------------- fused per-bucket: node hist + indptr + dinv + scatter ----------------
__global__ __launch_bounds__(256) void fine_kernel(const int* __restrict__ packed,
                                                   const int* __restrict__ bucketBase,
                                                   const int* __restrict__ bucketCnt,
                                                   int* __restrict__ csr_row,
                                                   int* __restrict__ indptr,
                                                   float* __restrict__ dinv, int N) {
    __shared__ int cnt[512];
    __shared__ int pre[512];
    __shared__ int fill[512];
    __shared__ int sm[256];
    int b = blockIdx.x;
    int t = threadIdx.x;
    int d0 = b << BKT_SHIFT;
    int nd = N - d0;
    if (nd > 512) nd = 512;
    cnt[t] = 0; cnt[t + 256] = 0;
    fill[t] = 0; fill[t + 256] = 0;
    __syncthreads();
    int beg = bucketBase[b];
    int end = beg + bucketCnt[b];
    for (int e = beg + t; e < end; e += 256)
        atomicAdd(&cnt[((unsigned)packed[e]) >> 17], 1);
    __syncthreads();
    int c0 = cnt[2 * t], c1 = cnt[2 * t + 1];
    int s = c0 + c1;
    sm[t] = s;
    __syncthreads();
    for (int off = 1; off < 256; off <<= 1) {
        int add = 0;
        if (t >= off) add = sm[t - off];
        __syncthreads();
        if (t >= off) sm[t] += add;
        __syncthreads();
    }
    int ex = sm[t] - s;
    pre[2 * t] = ex;
    pre[2 * t + 1] = ex + c0;
    __syncthreads();
    for (int dl = t; dl < nd; dl += 256) {
        indptr[d0 + dl] = beg + pre[dl];
        dinv[d0 + dl] = rsqrtf((float)(cnt[dl] + 1));
    }
    for (int e = beg + t; e < end; e += 256) {
        unsigned p = (unsigned)packed[e];
        int dl = (int)(p >> 17);
        int src = (int)(p & 0x1FFFFu);
        int pos = beg + pre[dl] + atomicAdd(&fill[dl], 1);
        csr_row[pos] = src;
    }
}

// ---------------- weight prep ----------------
__global__ __launch_bounds__(256) void prep_w1_kernel(const float* __restrict__ W1,
                                                      unsigned short* __restrict__ w1p) {
    int idx = blockIdx.x * 256 + threadIdx.x;
    int q = idx >> 14;
    int rem = idx & 16383;
    int c = rem >> 6, j = rem & 63;
    w1p[idx] = f2bf(W1[(size_t)(q * 64 + j) * HID_DIM + c]);
}

__global__ __launch_bounds__(256) void prep_w2_kernel(const float* __restrict__ W2,
                                                      unsigned short* __restrict__ w2p) {
    int idx = blockIdx.x * 256 + threadIdx.x;
    int c = idx >> 8, k = idx & 255;
    w2p[idx] = f2bf(W2[(size_t)k * OUT_DIM + c]);
}

// ---------------- MFMA MLP: r16 structure; epilogue writes fp8 hs ----------------
struct __align__(16) MlpSmem {
    union {
        struct {
            unsigned short xs[64][72];     // 9216 B
            unsigned short ws[256][72];    // 36864 B
        } p1;
        struct {
            unsigned short hid[64][264];   // 33792 B
            unsigned short w2s[32][264];   // 16896 B
        } p2;                              // 50688 B LDS -> 3 blocks/CU
    };
};

__device__ __forceinline__ float4 ldx1(const float* __restrict__ x, int row0, int N,
                                       int t, int i, int q) {
    int e = t * 4 + i * 1024;
    int r = e >> 6, j = e & 63;
    if (row0 + r < N) return *(const float4*)&x[(size_t)(row0 + r) * IN_DIM + q * 64 + j];
    return make_float4(0.f, 0.f, 0.f, 0.f);
}

__global__ __launch_bounds__(256, 3) void mlp_mfma_kernel(const float* __restrict__ x,
                                                          const unsigned short* __restrict__ w1p,
                                                          const float* __restrict__ b1,
                                                          const unsigned short* __restrict__ w2p,
                                                          const float* __restrict__ b2,
                                                          const float* __restrict__ dinv,
                                                          float* __restrict__ h0,
                                                          unsigned char* __restrict__ hs,
                                                          int N) {
    __shared__ MlpSmem sm;
    int t = threadIdx.x;
    int w = t >> 6, l = t & 63;
    int l15 = l & 15, l4 = l >> 4;
    int wr0 = w * 16;
    int row0 = blockIdx.x * 64;

    f32x4 acc[16];
#pragma unroll
    for (int i = 0; i < 16; ++i) acc[i] = (f32x4){0.f, 0.f, 0.f, 0.f};

    float4 xr0, xr1, xr2, xr3;
    uint4 wv0, wv1, wv2, wv3, wv4, wv5, wv6, wv7;

#define LOADX(q) do { \
        xr0 = ldx1(x, row0, N, t, 0, (q)); \
        xr1 = ldx1(x, row0, N, t, 1, (q)); \
        xr2 = ldx1(x, row0, N, t, 2, (q)); \
        xr3 = ldx1(x, row0, N, t, 3, (q)); \
    } while (0)
#define LOADW(q) do { \
        const unsigned short* _s = w1p + (q) * 16384; \
        wv0 = *(const uint4*)&_s[t * 8 + 0 * 2048]; \
        wv1 = *(const uint4*)&_s[t * 8 + 1 * 2048]; \
        wv2 = *(const uint4*)&_s[t * 8 + 2 * 2048]; \
        wv3 = *(const uint4*)&_s[t * 8 + 3 * 2048]; \
        wv4 = *(const uint4*)&_s[t * 8 + 4 * 2048]; \
        wv5 = *(const uint4*)&_s[t * 8 + 5 * 2048]; \
        wv6 = *(const uint4*)&_s[t * 8 + 6 * 2048]; \
        wv7 = *(const uint4*)&_s[t * 8 + 7 * 2048]; \
    } while (0)
#define STX(i, v) do { \
        int e = t * 4 + (i) * 1024; \
        int r = e >> 6, j = e & 63; \
        unsigned u0 = (unsigned)f2bf((v).x) | ((unsigned)f2bf((v).y) << 16); \
        unsigned u1 = (unsigned)f2bf((v).z) | ((unsigned)f2bf((v).w) << 16); \
        *(uint2*)&sm.p1.xs[r][j] = make_uint2(u0, u1); \
    } while (0)
#define STW(i, v) do { \
        int e = t * 8 + (i) * 2048; \
        int c = e >> 6, j = e & 63; \
        *(uint4*)&sm.p1.ws[c][j] = (v); \
    } while (0)

    LOADX(0);
    LOADW(0);

    for (int q = 0; q < 8; ++q) {
        __syncthreads();
        STX(0, xr0); STX(1, xr1); STX(2, xr2); STX(3, xr3);
        STW(0, wv0); STW(1, wv1); STW(2, wv2); STW(3, wv3);
        STW(4, wv4); STW(5, wv5); STW(6, wv6); STW(7, wv7);
        __syncthreads();
        if (q < 7) {
            LOADX(q + 1);
            LOADW(q + 1);
        }
#pragma unroll
        for (int s = 0; s < 2; ++s) {
            short8v a = *(const short8v*)&sm.p1.xs[wr0 + l15][s * 32 + l4 * 8];
#pragma unroll
            for (int tc = 0; tc < 16; ++tc) {
                short8v b = *(const short8v*)&sm.p1.ws[tc * 16 + l15][s * 32 + l4 * 8];
                acc[tc] = __builtin_amdgcn_mfma_f32_16x16x32_bf16(a, b, acc[tc], 0, 0, 0);
            }
        }
    }
    __syncthreads();  // xs/ws dead; p2 overlay begins

#pragma unroll
    for (int tc = 0; tc < 16; ++tc) {
        float bv = b1[tc * 16 + l15];
#pragma unroll
        for (int i = 0; i < 4; ++i) {
            float v = fmaxf(acc[tc][i] + bv, 0.f);
            sm.p2.hid[wr0 + l4 * 4 + i][tc * 16 + l15] = f2bf(v);
        }
    }

    f32x4 acc2[4];
#pragma unroll
    for (int i = 0; i < 4; ++i) acc2[i] = (f32x4){0.f, 0.f, 0.f, 0.f};

#pragma unroll
    for (int hf = 0; hf < 2; ++hf) {
#pragma unroll
        for (int i = 0; i < 4; ++i) {
            int e = t * 8 + i * 2048;
            int c = e >> 8, k = e & 255;
            *(uint4*)&sm.p2.w2s[c][k] = *(const uint4*)&w2p[hf * 8192 + e];
        }
        __syncthreads();
#pragma unroll
        for (int s = 0; s < 8; ++s) {
            short8v a = *(const short8v*)&sm.p2.hid[wr0 + l15][s * 32 + l4 * 8];
#pragma unroll
            for (int tcl = 0; tcl < 2; ++tcl) {
                short8v b = *(const short8v*)&sm.p2.w2s[tcl * 16 + l15][s * 32 + l4 * 8];
                acc2[hf * 2 + tcl] =
                    __builtin_amdgcn_mfma_f32_16x16x32_bf16(a, b, acc2[hf * 2 + tcl], 0, 0, 0);
            }
        }
        __syncthreads();
    }

    // epilogue2: h0 (fp32) + hs = fp8_e4m3(dinv * h0)
#pragma unroll
    for (int i = 0; i < 4; ++i) {
        int row = row0 + wr0 + l4 * 4 + i;
        if (row < N) {
            float dv = dinv[row];
#pragma unroll
            for (int tc = 0; tc < 4; ++tc) {
                float v = acc2[tc][i] + b2[tc * 16 + l15];
                h0[(size_t)row * OUT_DIM + tc * 16 + l15] = v;
                float sv = dv * v;
                int pk = __builtin_amdgcn_cvt_pk_fp8_f32(sv, sv, 0, false);
                hs[(size_t)row * OUT_DIM + tc * 16 + l15] = (unsigned char)(pk & 0xFF);
            }
        }
    }
#undef LOADX
#undef LOADW
#undef STX
#undef STW
}

// ---------------- propagation, fp8 rows, 32-edge mega-trips (8 gathers in flight) ----
// r17 lesson: halving gather bytes gained only 10% -> latency-bound, not line-rate.
// Fix: issue 8 independent gathers before any accumulate (1 waitcnt per 32 edges).
__global__ __launch_bounds__(256) void prop_fp8_kernel(const unsigned char* __restrict__ hs,
                                                       const float* __restrict__ h0,
                                                       const float* __restrict__ dinv,
                                                       const int* __restrict__ csr_row,
                                                       const int* __restrict__ indptr,
                                                       unsigned char* __restrict__ hs_out,
                                                       float* __restrict__ hfin,
                                                       int last, int N) {
    int node = blockIdx.x * 4 + (threadIdx.x >> 6);
    if (node >= N) return;
    int l = threadIdx.x & 63;
    int q = l >> 4, lf = l & 15;
    const unsigned* H = (const unsigned*)hs;   // [N][16] uints
    int beg = indptr[node], end = indptr[node + 1];
    float a0 = 0.f, a1 = 0.f, a2 = 0.f, a3 = 0.f;
#define ACCU(u) do { \
        f32x2 _f01 = __builtin_amdgcn_cvt_pk_f32_fp8((int)(u), false); \
        f32x2 _f23 = __builtin_amdgcn_cvt_pk_f32_fp8((int)(u), true);  \
        a0 += _f01[0]; a1 += _f01[1]; a2 += _f23[0]; a3 += _f23[1];    \
    } while (0)
    int e = beg;
    for (; e + 32 <= end; e += 32) {   // 32 edges: 8 idx loads, then 8 gathers in flight
        int r0 = csr_row[e + 0 + q];
        int r1 = csr_row[e + 4 + q];
        int r2 = csr_row[e + 8 + q];
        int r3 = csr_row[e + 12 + q];
        int r4 = csr_row[e + 16 + q];
        int r5 = csr_row[e + 20 + q];
        int r6 = csr_row[e + 24 + q];
        int r7 = csr_row[e + 28 + q];
        unsigned u0 = H[(size_t)r0 * 16 + lf];
        unsigned u1 = H[(size_t)r1 * 16 + lf];
        unsigned u2 = H[(size_t)r2 * 16 + lf];
        unsigned u3 = H[(size_t)r3 * 16 + lf];
        unsigned u4 = H[(size_t)r4 * 16 + lf];
        unsigned u5 = H[(size_t)r5 * 16 + lf];
        unsigned u6 = H[(size_t)r6 * 16 + lf];
        unsigned u7 = H[(size_t)r7 * 16 + lf];
        ACCU(u0); ACCU(u1); ACCU(u2); ACCU(u3);
        ACCU(u4); ACCU(u5); ACCU(u6); ACCU(u7);
    }
    for (; e + 8 <= end; e += 8) {
        int r0 = csr_row[e + q];
        int r1 = csr_row[e + 4 + q];
        unsigned u0 = H[(size_t)r0 * 16 + lf];
        unsigned u1 = H[(size_t)r1 * 16 + lf];
        ACCU(u0);
        ACCU(u1);
    }
    if (e + 4 <= end) {
        int r = csr_row[e + q];
        ACCU(H[(size_t)r * 16 + lf]);
        e += 4;
    }
    if (e + q < end) {  // masked tail (<4 edges)
        int r = csr_row[e + q];
        ACCU(H[(size_t)r * 16 + lf]);
    }
    // reduce across the 4 edge-slots (lane bits 4,5)
    a0 += __shfl_xor(a0, 16); a1 += __shfl_xor(a1, 16);
    a2 += __shfl_xor(a2, 16); a3 += __shfl_xor(a3, 16);
    a0 += __shfl_xor(a0, 32); a1 += __shfl_xor(a1, 32);
    a2 += __shfl_xor(a2, 32); a3 += __shfl_xor(a3, 32);
    ACCU(H[(size_t)node * 16 + lf]);  // self loop (once, post-reduce; uniform across quarters)
#undef ACCU
    float dcn = dinv[node];
    if (last) {
        float4 z = *(const float4*)&h0[(size_t)node * 64 + lf * 4];
        float o0 = (1.0f - ALPHA) * (dcn * a0) + ALPHA * z.x;
        float o1 = (1.0f - ALPHA) * (dcn * a1) + ALPHA * z.y;
        float o2 = (1.0f - ALPHA) * (dcn * a2) + ALPHA * z.z;
        float o3 = (1.0f - ALPHA) * (dcn * a3) + ALPHA * z.w;
        // fused log_softmax: all lanes hold full sums; row spans the 16 lf lanes
        float m = fmaxf(fmaxf(o0, o1), fmaxf(o2, o3));
        m = fmaxf(m, __shfl_xor(m, 1));
        m = fmaxf(m, __shfl_xor(m, 2));
        m = fmaxf(m, __shfl_xor(m, 4));
        m = fmaxf(m, __shfl_xor(m, 8));
        float s = expf(o0 - m) + expf(o1 - m) + expf(o2 - m) + expf(o3 - m);
        s += __shfl_xor(s, 1);
        s += __shfl_xor(s, 2);
        s += __shfl_xor(s, 4);
        s += __shfl_xor(s, 8);
        float lg = logf(s);
        if (q == 0) {
            float4 o;
            o.x = o0 - m - lg; o.y = o1 - m - lg; o.z = o2 - m - lg; o.w = o3 - m - lg;
            *(float4*)&hfin[(size_t)node * 64 + lf * 4] = o;
        }
    } else if (q == 0) {
        float4 z = *(const float4*)&h0[(size_t)node * 64 + lf * 4];
        float o0 = (1.0f - ALPHA) * (dcn * a0) + ALPHA * z.x;
        float o1 = (1.0f - ALPHA) * (dcn * a1) + ALPHA * z.y;
        float o2 = (1.0f - ALPHA) * (dcn * a2) + ALPHA * z.z;
        float o3 = (1.0f - ALPHA) * (dcn * a3) + ALPHA * z.w;
        int wpk = __builtin_amdgcn_cvt_pk_fp8_f32(dcn * o0, dcn * o1, 0, false);
        wpk = __builtin_amdgcn_cvt_pk_fp8_f32(dcn * o2, dcn * o3, wpk, true);
        ((unsigned*)hs_out)[(size_t)node * 16 + lf] = (unsigned)wpk;
    }
}

extern "C" void kernel_launch(void* const* d_in, const int* in_sizes, int n_in,
                              void* d_out, int out_size, void* d_ws, size_t ws_size,
                              hipStream_t stream) {
    const float* x  = (const float*)d_in[0];
    const int*   ei = (const int*)d_in[1];
    const float* W1 = (const float*)d_in[2];
    const float* b1 = (const float*)d_in[3];
    const float* W2 = (const float*)d_in[4];
    const float* b2 = (const float*)d_in[5];
    float* out = (float*)d_out;
    int N = in_sizes[0] / IN_DIM;
    int E = in_sizes[1] / 2;
    int nbkt = (N + 511) >> BKT_SHIFT;

    char* ws = (char*)d_ws;
    size_t off = 0;
    auto alloc = [&](size_t bytes) -> void* {
        void* p = ws + off;
        off += (bytes + 255) & ~(size_t)255;
        return p;
    };
    float* h0     = (float*)alloc((size_t)N * OUT_DIM * 4);
    float* dinv   = (float*)alloc((size_t)N * 4);
    int*   indptr = (int*)alloc((size_t)(N + 1) * 4);
    int*   bcnt   = (int*)alloc(256 * 4);
    int*   bbase  = (int*)alloc(256 * 4);
    int*   bfill  = (int*)alloc(256 * 4);
    int*   packed = (int*)alloc((size_t)E * 4);
    int*   csr_row= (int*)alloc((size_t)E * 4);
    unsigned short* w1p = (unsigned short*)alloc((size_t)IN_DIM * HID_DIM * 2);
    unsigned short* w2p = (unsigned short*)alloc((size_t)HID_DIM * OUT_DIM * 2);
    unsigned char* hsA = (unsigned char*)alloc((size_t)N * OUT_DIM);  // fp8
    unsigned char* hsB = (unsigned char*)alloc((size_t)N * OUT_DIM);  // fp8
    (void)ws_size; (void)n_in; (void)out_size;

    hipMemsetAsync(bcnt, 0, 256 * 4, stream);

    prep_w1_kernel<<<(IN_DIM * HID_DIM) / 256, 256, 0, stream>>>(W1, w1p);
    prep_w2_kernel<<<(HID_DIM * OUT_DIM) / 256, 256, 0, stream>>>(W2, w2p);

    int pgrid = (E + PART_EPB - 1) / PART_EPB;
    bucket_count_kernel<<<pgrid, 256, 0, stream>>>(ei, E, bcnt);
    bucket_scan_kernel<<<1, 256, 0, stream>>>(bcnt, bbase, bfill, indptr, E, N);
    partition_kernel<<<pgrid, 256, 0, stream>>>(ei, E, bfill, packed);
    fine_kernel<<<nbkt, 256, 0, stream>>>(packed, bbase, bcnt, csr_row, indptr, dinv, N);

    mlp_mfma_kernel<<<(N + 63) / 64, 256, 0, stream>>>(x, w1p, b1, w2p, b2, dinv,
                                                       h0, hsA, N);

    int pb = (N + 3) / 4;
    for (int it = 0; it < KPROP; ++it) {
        const unsigned char* hin = (it % 2 == 0) ? hsA : hsB;
        unsigned char* hout = (it % 2 == 0) ? hsB : hsA;
        int last = (it == KPROP - 1) ? 1 : 0;
        prop_fp8_kernel<<<pb, 256, 0, stream>>>(hin, h0, dinv, csr_row, indptr,
                                                hout, out, last, N);
    }
}

// Round 19
// 459.391 us; speedup vs baseline: 2.3141x; 1.0468x over previous
//
#include <hip/hip_runtime.h>

#define IN_DIM  512
#define HID_DIM 256
#define OUT_DIM 64
#define KPROP   5
#define ALPHA   0.1f

#define BKT_SHIFT 9            // 512 dst nodes per bucket
#define PART_EPB  8192         // edges per partition block

typedef short short8v __attribute__((ext_vector_type(8)));
typedef float f32x4   __attribute__((ext_vector_type(4)));
typedef float f32x2   __attribute__((ext_vector_type(2)));

__device__ __forceinline__ unsigned short f2bf(float f) {
    unsigned u = __builtin_bit_cast(unsigned, f);
    unsigned r = (u + 0x7FFFu + ((u >> 16) & 1u)) >> 16;
    return (unsigned short)r;
}

// ---------------- bucket-level edge count ----------------
__global__ __launch_bounds__(256) void bucket_count_kernel(const int* __restrict__ ei, int E,
                                                           int* __restrict__ bucketCnt) {
    __shared__ int hist[256];
    int t = threadIdx.x;
    hist[t] = 0;
    __syncthreads();
    int e0 = blockIdx.x * PART_EPB;
#pragma unroll 4
    for (int i = 0; i < PART_EPB / 256; ++i) {
        int e = e0 + i * 256 + t;
        if (e < E) atomicAdd(&hist[ei[E + e] >> BKT_SHIFT], 1);
    }
    __syncthreads();
    if (hist[t] > 0) atomicAdd(&bucketCnt[t], hist[t]);
}

// ---------------- bucket scan (1 block) ----------------
__global__ __launch_bounds__(256) void bucket_scan_kernel(const int* __restrict__ bucketCnt,
                                                          int* __restrict__ bucketBase,
                                                          int* __restrict__ bucketFill,
                                                          int* __restrict__ indptr,
                                                          int E, int N) {
    __shared__ int sm[256];
    int t = threadIdx.x;
    int v = bucketCnt[t];
    sm[t] = v;
    __syncthreads();
    for (int off = 1; off < 256; off <<= 1) {
        int add = 0;
        if (t >= off) add = sm[t - off];
        __syncthreads();
        if (t >= off) sm[t] += add;
        __syncthreads();
    }
    int base = sm[t] - v;
    bucketBase[t] = base;
    bucketFill[t] = base;
    if (t == 0) indptr[N] = E;
}

// ---------------- partition; packed = (dst&511)<<17 | src ----------------
__global__ __launch_bounds__(256) void partition_kernel(const int* __restrict__ ei, int E,
                                                        int* __restrict__ bucketFill,
                                                        int* __restrict__ packed) {
    __shared__ int hist[256];
    __shared__ int base[256];
    int t = threadIdx.x;
    int e0 = blockIdx.x * PART_EPB;
    hist[t] = 0;
    __syncthreads();
#pragma unroll 4
    for (int i = 0; i < PART_EPB / 256; ++i) {
        int e = e0 + i * 256 + t;
        if (e < E) atomicAdd(&hist[ei[E + e] >> BKT_SHIFT], 1);
    }
    __syncthreads();
    int cnt = hist[t];
    if (cnt > 0) base[t] = atomicAdd(&bucketFill[t], cnt);
    __syncthreads();
#pragma unroll 4
    for (int i = 0; i < PART_EPB / 256; ++i) {
        int e = e0 + i * 256 + t;
        if (e < E) {
            int dst = ei[E + e];
            int src = ei[e];
            int b = dst >> BKT_SHIFT;
            int pos = atomicAdd(&base[b], 1);
            packed[pos] = ((dst & 511) << 17) | src;
        }
    }
}

// ---------------- fused per-bucket: node hist + indptr + dinv + scatter ----------------
__global__ __launch_bounds__(256) void fine_kernel(const int* __restrict__ packed,
                                                   const int* __restrict__ bucketBase,
                                                   const int* __restrict__ bucketCnt,
                                                   int* __restrict__ csr_row,
                                                   int* __restrict__ indptr,
                                                   float* __restrict__ dinv, int N) {
    __shared__ int cnt[512];
    __shared__ int pre[512];
    __shared__ int fill[512];
    __shared__ int sm[256];
    int b = blockIdx.x;
    int t = threadIdx.x;
    int d0 = b << BKT_SHIFT;
    int nd = N - d0;
    if (nd > 512) nd = 512;
    cnt[t] = 0; cnt[t + 256] = 0;
    fill[t] = 0; fill[t + 256] = 0;
    __syncthreads();
    int beg = bucketBase[b];
    int end = beg + bucketCnt[b];
    for (int e = beg + t; e < end; e += 256)
        atomicAdd(&cnt[((unsigned)packed[e]) >> 17], 1);
    __syncthreads();
    int c0 = cnt[2 * t], c1 = cnt[2 * t + 1];
    int s = c0 + c1;
    sm[t] = s;
    __syncthreads();
    for (int off = 1; off < 256; off <<= 1) {
        int add = 0;
        if (t >= off) add = sm[t - off];
        __syncthreads();
        if (t >= off) sm[t] += add;
        __syncthreads();
    }
    int ex = sm[t] - s;
    pre[2 * t] = ex;
    pre[2 * t + 1] = ex + c0;
    __syncthreads();
    for (int dl = t; dl < nd; dl += 256) {
        indptr[d0 + dl] = beg + pre[dl];
        dinv[d0 + dl] = rsqrtf((float)(cnt[dl] + 1));
    }
    for (int e = beg + t; e < end; e += 256) {
        unsigned p = (unsigned)packed[e];
        int dl = (int)(p >> 17);
        int src = (int)(p & 0x1FFFFu);
        int pos = beg + pre[dl] + atomicAdd(&fill[dl], 1);
        csr_row[pos] = src;
    }
}

// ---------------- weight prep ----------------
__global__ __launch_bounds__(256) void prep_w1_kernel(const float* __restrict__ W1,
                                                      unsigned short* __restrict__ w1p) {
    int idx = blockIdx.x * 256 + threadIdx.x;
    int q = idx >> 14;
    int rem = idx & 16383;
    int c = rem >> 6, j = rem & 63;
    w1p[idx] = f2bf(W1[(size_t)(q * 64 + j) * HID_DIM + c]);
}

__global__ __launch_bounds__(256) void prep_w2_kernel(const float* __restrict__ W2,
                                                      unsigned short* __restrict__ w2p) {
    int idx = blockIdx.x * 256 + threadIdx.x;
    int c = idx >> 8, k = idx & 255;
    w2p[idx] = f2bf(W2[(size_t)k * OUT_DIM + c]);
}

// ---------------- MFMA MLP: r16 structure; epilogue writes fp8 hs ----------------
struct __align__(16) MlpSmem {
    union {
        struct {
            unsigned short xs[64][72];     // 9216 B
            unsigned short ws[256][72];    // 36864 B
        } p1;
        struct {
            unsigned short hid[64][264];   // 33792 B
            unsigned short w2s[32][264];   // 16896 B
        } p2;                              // 50688 B LDS -> 3 blocks/CU
    };
};

__device__ __forceinline__ float4 ldx1(const float* __restrict__ x, int row0, int N,
                                       int t, int i, int q) {
    int e = t * 4 + i * 1024;
    int r = e >> 6, j = e & 63;
    if (row0 + r < N) return *(const float4*)&x[(size_t)(row0 + r) * IN_DIM + q * 64 + j];
    return make_float4(0.f, 0.f, 0.f, 0.f);
}

__global__ __launch_bounds__(256, 3) void mlp_mfma_kernel(const float* __restrict__ x,
                                                          const unsigned short* __restrict__ w1p,
                                                          const float* __restrict__ b1,
                                                          const unsigned short* __restrict__ w2p,
                                                          const float* __restrict__ b2,
                                                          const float* __restrict__ dinv,
                                                          float* __restrict__ h0,
                                                          unsigned char* __restrict__ hs,
                                                          int N) {
    __shared__ MlpSmem sm;
    int t = threadIdx.x;
    int w = t >> 6, l = t & 63;
    int l15 = l & 15, l4 = l >> 4;
    int wr0 = w * 16;
    int row0 = blockIdx.x * 64;

    f32x4 acc[16];
#pragma unroll
    for (int i = 0; i < 16; ++i) acc[i] = (f32x4){0.f, 0.f, 0.f, 0.f};

    float4 xr0, xr1, xr2, xr3;
    uint4 wv0, wv1, wv2, wv3, wv4, wv5, wv6, wv7;

#define LOADX(q) do { \
        xr0 = ldx1(x, row0, N, t, 0, (q)); \
        xr1 = ldx1(x, row0, N, t, 1, (q)); \
        xr2 = ldx1(x, row0, N, t, 2, (q)); \
        xr3 = ldx1(x, row0, N, t, 3, (q)); \
    } while (0)
#define LOADW(q) do { \
        const unsigned short* _s = w1p + (q) * 16384; \
        wv0 = *(const uint4*)&_s[t * 8 + 0 * 2048]; \
        wv1 = *(const uint4*)&_s[t * 8 + 1 * 2048]; \
        wv2 = *(const uint4*)&_s[t * 8 + 2 * 2048]; \
        wv3 = *(const uint4*)&_s[t * 8 + 3 * 2048]; \
        wv4 = *(const uint4*)&_s[t * 8 + 4 * 2048]; \
        wv5 = *(const uint4*)&_s[t * 8 + 5 * 2048]; \
        wv6 = *(const uint4*)&_s[t * 8 + 6 * 2048]; \
        wv7 = *(const uint4*)&_s[t * 8 + 7 * 2048]; \
    } while (0)
#define STX(i, v) do { \
        int e = t * 4 + (i) * 1024; \
        int r = e >> 6, j = e & 63; \
        unsigned u0 = (unsigned)f2bf((v).x) | ((unsigned)f2bf((v).y) << 16); \
        unsigned u1 = (unsigned)f2bf((v).z) | ((unsigned)f2bf((v).w) << 16); \
        *(uint2*)&sm.p1.xs[r][j] = make_uint2(u0, u1); \
    } while (0)
#define STW(i, v) do { \
        int e = t * 8 + (i) * 2048; \
        int c = e >> 6, j = e & 63; \
        *(uint4*)&sm.p1.ws[c][j] = (v); \
    } while (0)

    LOADX(0);
    LOADW(0);

    for (int q = 0; q < 8; ++q) {
        __syncthreads();
        STX(0, xr0); STX(1, xr1); STX(2, xr2); STX(3, xr3);
        STW(0, wv0); STW(1, wv1); STW(2, wv2); STW(3, wv3);
        STW(4, wv4); STW(5, wv5); STW(6, wv6); STW(7, wv7);
        __syncthreads();
        if (q < 7) {
            LOADX(q + 1);
            LOADW(q + 1);
        }
#pragma unroll
        for (int s = 0; s < 2; ++s) {
            short8v a = *(const short8v*)&sm.p1.xs[wr0 + l15][s * 32 + l4 * 8];
#pragma unroll
            for (int tc = 0; tc < 16; ++tc) {
                short8v b = *(const short8v*)&sm.p1.ws[tc * 16 + l15][s * 32 + l4 * 8];
                acc[tc] = __builtin_amdgcn_mfma_f32_16x16x32_bf16(a, b, acc[tc], 0, 0, 0);
            }
        }
    }
    __syncthreads();  // xs/ws dead; p2 overlay begins

#pragma unroll
    for (int tc = 0; tc < 16; ++tc) {
        float bv = b1[tc * 16 + l15];
#pragma unroll
        for (int i = 0; i < 4; ++i) {
            float v = fmaxf(acc[tc][i] + bv, 0.f);
            sm.p2.hid[wr0 + l4 * 4 + i][tc * 16 + l15] = f2bf(v);
        }
    }

    f32x4 acc2[4];
#pragma unroll
    for (int i = 0; i < 4; ++i) acc2[i] = (f32x4){0.f, 0.f, 0.f, 0.f};

#pragma unroll
    for (int hf = 0; hf < 2; ++hf) {
#pragma unroll
        for (int i = 0; i < 4; ++i) {
            int e = t * 8 + i * 2048;
            int c = e >> 8, k = e & 255;
            *(uint4*)&sm.p2.w2s[c][k] = *(const uint4*)&w2p[hf * 8192 + e];
        }
        __syncthreads();
#pragma unroll
        for (int s = 0; s < 8; ++s) {
            short8v a = *(const short8v*)&sm.p2.hid[wr0 + l15][s * 32 + l4 * 8];
#pragma unroll
            for (int tcl = 0; tcl < 2; ++tcl) {
                short8v b = *(const short8v*)&sm.p2.w2s[tcl * 16 + l15][s * 32 + l4 * 8];
                acc2[hf * 2 + tcl] =
                    __builtin_amdgcn_mfma_f32_16x16x32_bf16(a, b, acc2[hf * 2 + tcl], 0, 0, 0);
            }
        }
        __syncthreads();
    }

    // epilogue2: h0 (fp32) + hs = fp8_e4m3(dinv * h0)
#pragma unroll
    for (int i = 0; i < 4; ++i) {
        int row = row0 + wr0 + l4 * 4 + i;
        if (row < N) {
            float dv = dinv[row];
#pragma unroll
            for (int tc = 0; tc < 4; ++tc) {
                float v = acc2[tc][i] + b2[tc * 16 + l15];
                h0[(size_t)row * OUT_DIM + tc * 16 + l15] = v;
                float sv = dv * v;
                int pk = __builtin_amdgcn_cvt_pk_fp8_f32(sv, sv, 0, false);
                hs[(size_t)row * OUT_DIM + tc * 16 + l15] = (unsigned char)(pk & 0xFF);
            }
        }
    }
#undef LOADX
#undef LOADW
#undef STX
#undef STW
}

// ---------------- propagation, fp8 rows, 8-lane/row layout (8 rows per gather instr) ----
// r18 lesson: mega-trips (more rows in flight) pay. Widen: lane = (q8 = l>>3
// edge-slot, lf8 = l&7 feature-octet); each lane loads uint2 (8 fp8) -> one
// gather instruction covers 8 rows; 32-edge trip = 4 gathers, 32 rows in flight.
__global__ __launch_bounds__(256) void prop_fp8_kernel(const unsigned char* __restrict__ hs,
                                                       const float* __restrict__ h0,
                                                       const float* __restrict__ dinv,
                                                       const int* __restrict__ csr_row,
                                                       const int* __restrict__ indptr,
                                                       unsigned char* __restrict__ hs_out,
                                                       float* __restrict__ hfin,
                                                       int last, int N) {
    int node = blockIdx.x * 4 + (threadIdx.x >> 6);
    if (node >= N) return;
    int l = threadIdx.x & 63;
    int q8 = l >> 3, lf8 = l & 7;
    const uint2* H2 = (const uint2*)hs;   // [N][8] uint2
    int beg = indptr[node], end = indptr[node + 1];
    float b0 = 0.f, b1v = 0.f, b2v = 0.f, b3 = 0.f;
    float b4 = 0.f, b5 = 0.f, b6 = 0.f, b7 = 0.f;
#define ACCU2(u2) do { \
        f32x2 _p0 = __builtin_amdgcn_cvt_pk_f32_fp8((int)(u2).x, false); \
        f32x2 _p1 = __builtin_amdgcn_cvt_pk_f32_fp8((int)(u2).x, true);  \
        f32x2 _p2 = __builtin_amdgcn_cvt_pk_f32_fp8((int)(u2).y, false); \
        f32x2 _p3 = __builtin_amdgcn_cvt_pk_f32_fp8((int)(u2).y, true);  \
        b0 += _p0[0]; b1v += _p0[1]; b2v += _p1[0]; b3 += _p1[1];        \
        b4 += _p2[0]; b5 += _p2[1]; b6 += _p3[0]; b7 += _p3[1];          \
    } while (0)
    int e = beg;
    for (; e + 32 <= end; e += 32) {   // 32 edges: 4 idx loads, 4 gathers (32 rows in flight)
        int r0 = csr_row[e + 0 + q8];
        int r1 = csr_row[e + 8 + q8];
        int r2 = csr_row[e + 16 + q8];
        int r3 = csr_row[e + 24 + q8];
        uint2 u0 = H2[(size_t)r0 * 8 + lf8];
        uint2 u1 = H2[(size_t)r1 * 8 + lf8];
        uint2 u2 = H2[(size_t)r2 * 8 + lf8];
        uint2 u3 = H2[(size_t)r3 * 8 + lf8];
        ACCU2(u0); ACCU2(u1); ACCU2(u2); ACCU2(u3);
    }
    for (; e + 8 <= end; e += 8) {
        int r = csr_row[e + q8];
        uint2 u = H2[(size_t)r * 8 + lf8];
        ACCU2(u);
    }
    if (e + q8 < end) {  // masked tail (<8 edges)
        int r = csr_row[e + q8];
        uint2 u = H2[(size_t)r * 8 + lf8];
        ACCU2(u);
    }
    // reduce across the 8 edge-slots (lane bits 3,4,5)
    b0 += __shfl_xor(b0, 8);  b1v += __shfl_xor(b1v, 8);
    b2v += __shfl_xor(b2v, 8); b3 += __shfl_xor(b3, 8);
    b4 += __shfl_xor(b4, 8);  b5 += __shfl_xor(b5, 8);
    b6 += __shfl_xor(b6, 8);  b7 += __shfl_xor(b7, 8);
    b0 += __shfl_xor(b0, 16); b1v += __shfl_xor(b1v, 16);
    b2v += __shfl_xor(b2v, 16); b3 += __shfl_xor(b3, 16);
    b4 += __shfl_xor(b4, 16); b5 += __shfl_xor(b5, 16);
    b6 += __shfl_xor(b6, 16); b7 += __shfl_xor(b7, 16);
    b0 += __shfl_xor(b0, 32); b1v += __shfl_xor(b1v, 32);
    b2v += __shfl_xor(b2v, 32); b3 += __shfl_xor(b3, 32);
    b4 += __shfl_xor(b4, 32); b5 += __shfl_xor(b5, 32);
    b6 += __shfl_xor(b6, 32); b7 += __shfl_xor(b7, 32);
    {
        uint2 us = H2[(size_t)node * 8 + lf8];  // self loop (post-reduce, uniform)
        ACCU2(us);
    }
#undef ACCU2
    float dcn = dinv[node];
    float4 za = *(const float4*)&h0[(size_t)node * 64 + lf8 * 8];
    float4 zb = *(const float4*)&h0[(size_t)node * 64 + lf8 * 8 + 4];
    float o0 = (1.0f - ALPHA) * (dcn * b0) + ALPHA * za.x;
    float o1 = (1.0f - ALPHA) * (dcn * b1v) + ALPHA * za.y;
    float o2 = (1.0f - ALPHA) * (dcn * b2v) + ALPHA * za.z;
    float o3 = (1.0f - ALPHA) * (dcn * b3) + ALPHA * za.w;
    float o4 = (1.0f - ALPHA) * (dcn * b4) + ALPHA * zb.x;
    float o5 = (1.0f - ALPHA) * (dcn * b5) + ALPHA * zb.y;
    float o6 = (1.0f - ALPHA) * (dcn * b6) + ALPHA * zb.z;
    float o7 = (1.0f - ALPHA) * (dcn * b7) + ALPHA * zb.w;
    if (last) {
        // fused log_softmax: row lives in the 8 lf8 lanes of slot q8==0;
        // xor {1,2,4} is closed within each 8-lane group.
        float m = fmaxf(fmaxf(fmaxf(o0, o1), fmaxf(o2, o3)),
                        fmaxf(fmaxf(o4, o5), fmaxf(o6, o7)));
        m = fmaxf(m, __shfl_xor(m, 1));
        m = fmaxf(m, __shfl_xor(m, 2));
        m = fmaxf(m, __shfl_xor(m, 4));
        float s = expf(o0 - m) + expf(o1 - m) + expf(o2 - m) + expf(o3 - m) +
                  expf(o4 - m) + expf(o5 - m) + expf(o6 - m) + expf(o7 - m);
        s += __shfl_xor(s, 1);
        s += __shfl_xor(s, 2);
        s += __shfl_xor(s, 4);
        float lg = logf(s);
        if (q8 == 0) {
            float4 oa, ob;
            oa.x = o0 - m - lg; oa.y = o1 - m - lg; oa.z = o2 - m - lg; oa.w = o3 - m - lg;
            ob.x = o4 - m - lg; ob.y = o5 - m - lg; ob.z = o6 - m - lg; ob.w = o7 - m - lg;
            *(float4*)&hfin[(size_t)node * 64 + lf8 * 8] = oa;
            *(float4*)&hfin[(size_t)node * 64 + lf8 * 8 + 4] = ob;
        }
    } else if (q8 == 0) {
        int pk0 = __builtin_amdgcn_cvt_pk_fp8_f32(dcn * o0, dcn * o1, 0, false);
        pk0 = __builtin_amdgcn_cvt_pk_fp8_f32(dcn * o2, dcn * o3, pk0, true);
        int pk1 = __builtin_amdgcn_cvt_pk_fp8_f32(dcn * o4, dcn * o5, 0, false);
        pk1 = __builtin_amdgcn_cvt_pk_fp8_f32(dcn * o6, dcn * o7, pk1, true);
        ((uint2*)hs_out)[(size_t)node * 8 + lf8] = make_uint2((unsigned)pk0, (unsigned)pk1);
    }
}

extern "C" void kernel_launch(void* const* d_in, const int* in_sizes, int n_in,
                              void* d_out, int out_size, void* d_ws, size_t ws_size,
                              hipStream_t stream) {
    const float* x  = (const float*)d_in[0];
    const int*   ei = (const int*)d_in[1];
    const float* W1 = (const float*)d_in[2];
    const float* b1 = (const float*)d_in[3];
    const float* W2 = (const float*)d_in[4];
    const float* b2 = (const float*)d_in[5];
    float* out = (float*)d_out;
    int N = in_sizes[0] / IN_DIM;
    int E = in_sizes[1] / 2;
    int nbkt = (N + 511) >> BKT_SHIFT;

    char* ws = (char*)d_ws;
    size_t off = 0;
    auto alloc = [&](size_t bytes) -> void* {
        void* p = ws + off;
        off += (bytes + 255) & ~(size_t)255;
        return p;
    };
    float* h0     = (float*)alloc((size_t)N * OUT_DIM * 4);
    float* dinv   = (float*)alloc((size_t)N * 4);
    int*   indptr = (int*)alloc((size_t)(N + 1) * 4);
    int*   bcnt   = (int*)alloc(256 * 4);
    int*   bbase  = (int*)alloc(256 * 4);
    int*   bfill  = (int*)alloc(256 * 4);
    int*   packed = (int*)alloc((size_t)E * 4);
    int*   csr_row= (int*)alloc((size_t)E * 4);
    unsigned short* w1p = (unsigned short*)alloc((size_t)IN_DIM * HID_DIM * 2);
    unsigned short* w2p = (unsigned short*)alloc((size_t)HID_DIM * OUT_DIM * 2);
    unsigned char* hsA = (unsigned char*)alloc((size_t)N * OUT_DIM);  // fp8
    unsigned char* hsB = (unsigned char*)alloc((size_t)N * OUT_DIM);  // fp8
    (void)ws_size; (void)n_in; (void)out_size;

    hipMemsetAsync(bcnt, 0, 256 * 4, stream);

    prep_w1_kernel<<<(IN_DIM * HID_DIM) / 256, 256, 0, stream>>>(W1, w1p);
    prep_w2_kernel<<<(HID_DIM * OUT_DIM) / 256, 256, 0, stream>>>(W2, w2p);

    int pgrid = (E + PART_EPB - 1) / PART_EPB;
    bucket_count_kernel<<<pgrid, 256, 0, stream>>>(ei, E, bcnt);
    bucket_scan_kernel<<<1, 256, 0, stream>>>(bcnt, bbase, bfill, indptr, E, N);
    partition_kernel<<<pgrid, 256, 0, stream>>>(ei, E, bfill, packed);
    fine_kernel<<<nbkt, 256, 0, stream>>>(packed, bbase, bcnt, csr_row, indptr, dinv, N);

    mlp_mfma_kernel<<<(N + 63) / 64, 256, 0, stream>>>(x, w1p, b1, w2p, b2, dinv,
                                                       h0, hsA, N);

    int pb = (N + 3) / 4;
    for (int it = 0; it < KPROP; ++it) {
        const unsigned char* hin = (it % 2 == 0) ? hsA : hsB;
        unsigned char* hout = (it % 2 == 0) ? hsB : hsA;
        int last = (it == KPROP - 1) ? 1 : 0;
        prop_fp8_kernel<<<pb, 256, 0, stream>>>(hin, h0, dinv, csr_row, indptr,
                                                hout, out, last, N);
    }
}